// Round 10
// baseline (514.778 us; speedup 1.0000x reference)
//
#include <hip/hip_runtime.h>
#include <hip/hip_bf16.h>
#include <cmath>

// B=4, N=1024, DIM=1024, H=16, DH=64, M=16, QK_SCALE=10
typedef __attribute__((ext_vector_type(8))) short short8;
typedef __attribute__((ext_vector_type(4))) float f32x4;

__device__ __forceinline__ unsigned short to_bf(float f) {
  __hip_bfloat16 h = __float2bfloat16(f);
  return __builtin_bit_cast(unsigned short, h);
}

// async global->LDS, 16B per lane; LDS dest must be wave-uniform base + lane*16
__device__ __forceinline__ void gload_lds16(const void* g, void* l) {
  __builtin_amdgcn_global_load_lds((const __attribute__((address_space(1))) void*)g,
                                   (__attribute__((address_space(3))) void*)l, 16, 0, 0);
}

// sS row-col XOR swizzle: spreads the 4 i-rows of a wave across both 16-bank
// halves -> QK 4B stores and premix 4B reads are 2-way (free) instead of 4-way.
#define SWZS(ir) ((((ir) & 1) << 4) | (((ir) & 6) << 1))

// -------- fp32 -> bf16 elementwise ------------------------------------------
__global__ __launch_bounds__(256)
void cvt_bf16x4(const float* __restrict__ in, unsigned short* __restrict__ out, int n4)
{
  int i = blockIdx.x * 256 + threadIdx.x;
  if (i < n4) {
    float4 v = ((const float4*)in)[i];
    ushort4 o;
    o.x = to_bf(v.x); o.y = to_bf(v.y); o.z = to_bf(v.z); o.w = to_bf(v.w);
    ((ushort4*)out)[i] = o;
  }
}

// -------- W [1024 k][1024 n] fp32 -> WT [n][k] bf16 -------------------------
__global__ __launch_bounds__(256)
void transpose_to_bf(const float* __restrict__ W, unsigned short* __restrict__ WT)
{
  __shared__ float tile[64][65];
  const int n0 = blockIdx.x * 64, k0 = blockIdx.y * 64;
  const int t = threadIdx.x, c = t & 63, r4 = t >> 6;
#pragma unroll
  for (int q = 0; q < 16; ++q) {
    int r = (q << 2) + r4;
    tile[r][c] = W[(size_t)(k0 + r) * 1024 + n0 + c];
  }
  __syncthreads();
#pragma unroll
  for (int q = 0; q < 16; ++q) {
    int r = (q << 2) + r4;
    WT[(size_t)(n0 + r) * 1024 + k0 + c] = to_bf(tile[c][r]);
  }
}

// -------- 4 weights -> one WT4 [4096 n][1024 k] bf16 (z = weight) -----------
__global__ __launch_bounds__(256)
void transpose4_to_bf(const float* __restrict__ W0, const float* __restrict__ W1,
                      const float* __restrict__ W2, const float* __restrict__ W3,
                      unsigned short* __restrict__ WT4)
{
  __shared__ float tile[64][65];
  const float* W = (blockIdx.z == 0) ? W0 : (blockIdx.z == 1) ? W1
                 : (blockIdx.z == 2) ? W2 : W3;
  const int n0 = blockIdx.x * 64, k0 = blockIdx.y * 64;
  const int t = threadIdx.x, c = t & 63, r4 = t >> 6;
#pragma unroll
  for (int q = 0; q < 16; ++q) {
    int r = (q << 2) + r4;
    tile[r][c] = W[(size_t)(k0 + r) * 1024 + n0 + c];
  }
  __syncthreads();
  const size_t zoff = (size_t)blockIdx.z << 10;
#pragma unroll
  for (int q = 0; q < 16; ++q) {
    int r = (q << 2) + r4;
    WT4[(zoff + n0 + r) * 1024 + k0 + c] = to_bf(tile[c][r]);
  }
}

// ---- bf16 MFMA GEMM, 128x64 tile, BK=32 -- R16: global_load_lds staging ----
// m97-style: double-buffered LINEAR LDS (staging byte = t*16, exactly the
// wave-uniform-base+lane*16 pattern global_load_lds requires). R9 proved the
// resulting 8-way fragment-read conflicts are hidden by TLP here, so padding
// is dropped. Removes the VGPR round-trip + addr-calc from staging (+67% on
// the guide's ladder, m193).
__global__ __launch_bounds__(256)
void gemm_bf128(const unsigned short* __restrict__ A, const unsigned short* __restrict__ BT,
                float* __restrict__ C)
{
  __shared__ __align__(16) unsigned short Ab[2][128 * 32];
  __shared__ __align__(16) unsigned short Bb[2][64 * 32];
  const int t = threadIdx.x, lane = t & 63, w = t >> 6;
  const int m = lane & 15, quad = lane >> 4;
  const int row0 = blockIdx.y << 7, col0 = blockIdx.x << 6;

  const int r0 = t >> 2, kp0 = t & 3;

  f32x4 acc[2][4];
#pragma unroll
  for (int mi = 0; mi < 2; ++mi)
#pragma unroll
    for (int ni = 0; ni < 4; ++ni) acc[mi][ni] = (f32x4){0.f, 0.f, 0.f, 0.f};

  const unsigned short* gA0 = A + (size_t)(row0 + r0) * 1024 + kp0 * 8;
  const unsigned short* gA1 = A + (size_t)(row0 + 64 + r0) * 1024 + kp0 * 8;
  const unsigned short* gB0 = BT + (size_t)(col0 + r0) * 1024 + kp0 * 8;
  const int wb = w << 10;   // per-wave LDS byte base (lane-uniform)

#define STAGE_WO(buf, kk) do {                                            \
    gload_lds16(gA0 + (kk), (char*)&Ab[buf][0] + wb);                     \
    gload_lds16(gA1 + (kk), (char*)&Ab[buf][0] + 4096 + wb);              \
    gload_lds16(gB0 + (kk), (char*)&Bb[buf][0] + wb);                     \
  } while (0)

  STAGE_WO(0, 0);
  __syncthreads();
  int cur = 0;
  for (int kk = 0; kk < 1024; kk += 32) {
    if (kk + 32 < 1024) STAGE_WO(cur ^ 1, kk + 32);
    short8 af[2], bf[4];
#pragma unroll
    for (int mi = 0; mi < 2; ++mi)
      af[mi] = *(const short8*)((char*)&Ab[cur][0] + ((w << 5) + (mi << 4) + m) * 64 + quad * 16);
#pragma unroll
    for (int ni = 0; ni < 4; ++ni)
      bf[ni] = *(const short8*)((char*)&Bb[cur][0] + ((ni << 4) + m) * 64 + quad * 16);
#pragma unroll
    for (int mi = 0; mi < 2; ++mi)
#pragma unroll
      for (int ni = 0; ni < 4; ++ni)
        acc[mi][ni] = __builtin_amdgcn_mfma_f32_16x16x32_bf16(af[mi], bf[ni], acc[mi][ni], 0, 0, 0);
    __syncthreads();   // drains vmcnt -> buf[cur^1] staged; readers of buf[cur] done
    cur ^= 1;
  }
#pragma unroll
  for (int mi = 0; mi < 2; ++mi)
#pragma unroll
    for (int ni = 0; ni < 4; ++ni)
#pragma unroll
      for (int reg = 0; reg < 4; ++reg) {
        int mrow = row0 + (w << 5) + (mi << 4) + (quad << 2) + reg;
        int ncol = col0 + (ni << 4) + m;
        C[((size_t)mrow << 10) + ncol] = acc[mi][ni][reg];
      }
}

// ---- fused QKVG GEMM: xb[4096x1024] @ WT4^T -> 4 sector outputs ------------
// grid (64,32); sector = col0>>10 block-uniform: 0=q_lin 1=k_lin
// 2=vallT bf16 (V^T layout) 3=vgbuf sigmoid(.+b_vg). R16 global_load_lds.
__global__ __launch_bounds__(256)
void gemm_qkvg(const unsigned short* __restrict__ A, const unsigned short* __restrict__ BT4,
               float* __restrict__ q_lin, float* __restrict__ k_lin,
               unsigned short* __restrict__ vallT, float* __restrict__ vgbuf,
               const float* __restrict__ b_vg)
{
  __shared__ __align__(16) unsigned short Ab[2][128 * 32];
  __shared__ __align__(16) unsigned short Bb[2][64 * 32];
  const int t = threadIdx.x, lane = t & 63, w = t >> 6;
  const int m = lane & 15, quad = lane >> 4;
  const int row0 = blockIdx.y << 7, col0 = blockIdx.x << 6;
  const int sector = col0 >> 10;

  const int r0 = t >> 2, kp0 = t & 3;

  f32x4 acc[2][4];
#pragma unroll
  for (int mi = 0; mi < 2; ++mi)
#pragma unroll
    for (int ni = 0; ni < 4; ++ni) acc[mi][ni] = (f32x4){0.f, 0.f, 0.f, 0.f};

  const unsigned short* gA0 = A + (size_t)(row0 + r0) * 1024 + kp0 * 8;
  const unsigned short* gA1 = A + (size_t)(row0 + 64 + r0) * 1024 + kp0 * 8;
  const unsigned short* gB0 = BT4 + (size_t)(col0 + r0) * 1024 + kp0 * 8;
  const int wb = w << 10;

#define STAGE_QK(buf, kk) do {                                            \
    gload_lds16(gA0 + (kk), (char*)&Ab[buf][0] + wb);                     \
    gload_lds16(gA1 + (kk), (char*)&Ab[buf][0] + 4096 + wb);              \
    gload_lds16(gB0 + (kk), (char*)&Bb[buf][0] + wb);                     \
  } while (0)

  STAGE_QK(0, 0);
  __syncthreads();
  int cur = 0;
  for (int kk = 0; kk < 1024; kk += 32) {
    if (kk + 32 < 1024) STAGE_QK(cur ^ 1, kk + 32);
    short8 af[2], bf[4];
#pragma unroll
    for (int mi = 0; mi < 2; ++mi)
      af[mi] = *(const short8*)((char*)&Ab[cur][0] + ((w << 5) + (mi << 4) + m) * 64 + quad * 16);
#pragma unroll
    for (int ni = 0; ni < 4; ++ni)
      bf[ni] = *(const short8*)((char*)&Bb[cur][0] + ((ni << 4) + m) * 64 + quad * 16);
#pragma unroll
    for (int mi = 0; mi < 2; ++mi)
#pragma unroll
      for (int ni = 0; ni < 4; ++ni)
        acc[mi][ni] = __builtin_amdgcn_mfma_f32_16x16x32_bf16(af[mi], bf[ni], acc[mi][ni], 0, 0, 0);
    __syncthreads();
    cur ^= 1;
  }
  // C/D layout: col = lane&15, row = quad*4 + reg
#pragma unroll
  for (int mi = 0; mi < 2; ++mi)
#pragma unroll
    for (int ni = 0; ni < 4; ++ni)
#pragma unroll
      for (int reg = 0; reg < 4; ++reg) {
        int mrow = row0 + (w << 5) + (mi << 4) + (quad << 2) + reg;
        int nl = (col0 & 1023) + (ni << 4) + m;
        float v = acc[mi][ni][reg];
        if (sector == 0) {
          q_lin[((size_t)mrow << 10) + nl] = v;
        } else if (sector == 1) {
          k_lin[((size_t)mrow << 10) + nl] = v;
        } else if (sector == 2) {
          int bb = mrow >> 10, nn = mrow & 1023;
          vallT[((size_t)((bb << 10) + nl)) * 1056 + 16 + nn] = to_bf(v);
        } else {
          float s = v + b_vg[nl];
          vgbuf[((size_t)mrow << 10) + nl] = 1.f / (1.f + __expf(-s));
        }
      }
}

// ---- fused head-gate projection: hg = sigmoid(x @ W_hg + b_hg) -------------
__global__ __launch_bounds__(256)
void hgate_proj(const float* __restrict__ x, const float* __restrict__ W,
                const float* __restrict__ bias, float* __restrict__ hg)
{
  int G = blockIdx.x * 256 + threadIdx.x;
  int row = G >> 4, h = G & 15;
  const float4* x4 = (const float4*)(x + ((size_t)row << 10));
  float acc = 0.f;
#pragma unroll 4
  for (int k4 = 0; k4 < 256; ++k4) {
    float4 xv = x4[k4];
    int kb = k4 << 2;
    acc += xv.x * W[(kb + 0) * 16 + h] + xv.y * W[(kb + 1) * 16 + h]
         + xv.z * W[(kb + 2) * 16 + h] + xv.w * W[(kb + 3) * 16 + h];
  }
  float v = acc + bias[h];
  hg[(row << 4) + h] = 1.f / (1.f + __expf(-v));
}

// ------ q post: l2norm * scale * QK_SCALE + rope -> bf16 qb -----------------
__global__ __launch_bounds__(256)
void q_post_bf(const float* __restrict__ q_lin, const float* __restrict__ scale,
               const float* __restrict__ freqs, unsigned short* __restrict__ qb)
{
  int gid = blockIdx.x * 256 + threadIdx.x;
  int d = gid & 63;
  int row = gid >> 6;
  int h = row & 15;
  int n = (row >> 4) & 1023;
  float v = q_lin[gid];
  float ss = v * v;
#pragma unroll
  for (int off = 32; off; off >>= 1) ss += __shfl_xor(ss, off);
  v = v / fmaxf(sqrtf(ss), 1e-12f) * scale[(h << 6) + d];
  float f = freqs[(n << 6) + d];
  float other = __shfl_xor(v, 1);
  float rot = (d & 1) ? other : -other;
  qb[gid] = to_bf((v * cosf(f) + rot * sinf(f)) * 10.f);   // QK_SCALE folded
}

// ------ k post: l2norm*scale + rope, bf16 into kall (row stride 1056) -------
__global__ __launch_bounds__(256)
void k_post_bf(const float* __restrict__ k_lin, const float* __restrict__ scale,
               const float* __restrict__ freqs, unsigned short* __restrict__ kall)
{
  int gid = blockIdx.x * 256 + threadIdx.x;
  int d = gid & 63;
  int row = gid >> 6;
  int h = row & 15;
  int n = (row >> 4) & 1023;
  int b = row >> 14;
  float v = k_lin[gid];
  float ss = v * v;
#pragma unroll
  for (int off = 32; off; off >>= 1) ss += __shfl_xor(ss, off);
  v = v / fmaxf(sqrtf(ss), 1e-12f) * scale[(h << 6) + d];
  float f = freqs[(n << 6) + d];
  float other = __shfl_xor(v, 1);
  float rot = (d & 1) ? other : -other;
  float out = v * cosf(f) + rot * sinf(f);
  kall[(size_t)(b * 1056 + 16 + n) * 1024 + (h << 6) + d] = to_bf(out);
}

// ------ memory slots into kall rows 0..15 and vallT cols 0..15 --------------
__global__ __launch_bounds__(256)
void mem_build(const float* __restrict__ mem_k, const float* __restrict__ mem_v,
               const float* __restrict__ k_scale,
               unsigned short* __restrict__ kall, unsigned short* __restrict__ vallT)
{
  int gid = blockIdx.x * 256 + threadIdx.x;   // 16384 = H*M*64
  int d = gid & 63;
  int row = gid >> 6;            // h*M + mm
  int h = row >> 4, mm = row & 15;
  float v = mem_k[gid];
  float ss = v * v;
#pragma unroll
  for (int off = 32; off; off >>= 1) ss += __shfl_xor(ss, off);
  unsigned short kb = to_bf(v / fmaxf(sqrtf(ss), 1e-12f) * k_scale[(h << 6) + d]);
  unsigned short vb = to_bf(mem_v[gid]);
#pragma unroll
  for (int b = 0; b < 4; ++b) {
    kall[(size_t)(b * 1056 + mm) * 1024 + (h << 6) + d] = kb;
    vallT[(size_t)((b << 10) + (h << 6) + d) * 1056 + mm] = vb;
  }
}

// ================= two-pass MFMA attention, flat-balanced ===================
// Attention = R7-proven best (pv2 natural alloc 168 VGPR, 158.5 us; grid 768).
// Hardened: R1/R5 pins spilled, R8 restructure spilled -- do not touch.

// ---- pass 1: denominators L[b][i][g] via atomicAdd -------------------------
__global__ __launch_bounds__(256)
void attn_lsum(const unsigned short* __restrict__ qb, const unsigned short* __restrict__ kall,
               const float* __restrict__ W_pre, float* __restrict__ Lbuf)
{
  __shared__ float sS[16 * 16 * 32];            // [h][i][j 0..31], swizzled cols
  __shared__ f32x4 sWpre4[64];

  const int t = threadIdx.x, lane = t & 63, w = t >> 6;
  const int m = lane & 15, quad = lane >> 4;
  if (t < 64) {
    int h = t >> 2, p4 = t & 3;
    sWpre4[t] = (f32x4){W_pre[(4 * p4 + 0) * 16 + h], W_pre[(4 * p4 + 1) * 16 + h],
                        W_pre[(4 * p4 + 2) * 16 + h], W_pre[(4 * p4 + 3) * 16 + h]};
  }

  const int blk = blockIdx.x;                   // grid 768
  const int u0 = (4352 * blk) / 768, u1 = (4352 * (blk + 1)) / 768;
  if (u0 == u1) return;

  int accu = 0, bi = 0;
  while (true) {
    int un = (((bi & 63) + 1) >> 1) + 1;
    if (accu + un > u0) break;
    accu += un; ++bi;
  }
  int b = bi >> 6, it = bi & 63, uoff = u0 - accu;

  short8 afr[4][2];
  float partL[16];
  bool fresh = true;

  for (int u = u0; u < u1; ++u) {
    const int i0 = it << 4;
    if (fresh) {
#pragma unroll
      for (int hh = 0; hh < 4; ++hh)
#pragma unroll
        for (int kk = 0; kk < 2; ++kk)
          afr[hh][kk] = *(const short8*)(qb + (((size_t)(b << 10) + i0 + m) << 10)
                                         + ((w << 2) + hh) * 64 + kk * 32 + quad * 8);
#pragma unroll
      for (int g = 0; g < 16; ++g) partL[g] = 0.f;
      fresh = false;
    }
    const int j0 = uoff << 5;
    // ---- QK: both 16-j subtiles -> sS ----
#pragma unroll
    for (int sub = 0; sub < 2; ++sub) {
      const int js = j0 + (sub << 4);
#pragma unroll
      for (int hh = 0; hh < 4; ++hh) {
        f32x4 s = (f32x4){0.f, 0.f, 0.f, 0.f};
#pragma unroll
        for (int kk = 0; kk < 2; ++kk) {
          short8 bfr = *(const short8*)(kall + ((size_t)(b * 1056 + js + m) << 10)
                                        + ((w << 2) + hh) * 64 + kk * 32 + quad * 8);
          s = __builtin_amdgcn_mfma_f32_16x16x32_bf16(afr[hh][kk], bfr, s, 0, 0, 0);
        }
#pragma unroll
        for (int reg = 0; reg < 4; ++reg) {
          int irow = (quad << 2) + reg;
          sS[(((w << 2) + hh) * 16 + irow) * 32 + (((sub << 4) + m) ^ SWZS(irow))] = s[reg];
        }
      }
    }
    __syncthreads();
    // ---- packed premix + exp; 2 columns per thread ----
    {
      const int i_l = t >> 4, j_l = t & 15;
      const int ig = i0 + i_l;
      const int vs = SWZS(i_l);
      const int sc0 = j_l ^ vs, sc1 = (16 + j_l) ^ vs;
      float ch0[16], ch1[16];
#pragma unroll
      for (int h = 0; h < 16; ++h) {
        ch0[h] = sS[(h * 16 + i_l) * 32 + sc0];
        ch1[h] = sS[(h * 16 + i_l) * 32 + sc1];
      }
      f32x4 a0[4], a1[4];
#pragma unroll
      for (int p = 0; p < 4; ++p) { a0[p] = (f32x4){0.f,0.f,0.f,0.f}; a1[p] = a0[p]; }
#pragma unroll
      for (int h = 0; h < 16; ++h) {
        float c0 = ch0[h], c1 = ch1[h];
#pragma unroll
        for (int p = 0; p < 4; ++p) {
          f32x4 wv = sWpre4[(h << 2) + p];
          a0[p] += wv * c0;
          a1[p] += wv * c1;
        }
      }
      const bool ok0 = (j0 + j_l) <= ig + 16;
      const bool ok1 = (j0 + 16 + j_l) <= ig + 16;
#pragma unroll
      for (int p = 0; p < 4; ++p)
#pragma unroll
        for (int e = 0; e < 4; ++e) {
          float v0 = ok0 ? __expf(a0[p][e] - 20.f) : 0.f;
          float v1 = ok1 ? __expf(a1[p][e] - 20.f) : 0.f;
          partL[(p << 2) + e] += v0 + v1;
        }
    }
    __syncthreads();
    ++uoff;
    if (uoff == ((it + 1) >> 1) + 1) {
#pragma unroll
      for (int g = 0; g < 16; ++g) {
        float v = partL[g];
        v += __shfl_xor(v, 1); v += __shfl_xor(v, 2);
        v += __shfl_xor(v, 4); v += __shfl_xor(v, 8);
        if (m == 0)
          atomicAdd(&Lbuf[(((size_t)(b << 10) + i0 + (w << 2) + quad) << 4) + g], v);
      }
      ++bi; b = bi >> 6; it = bi & 63; uoff = 0; fresh = true;
    }
  }
  if (!fresh) {
    const int i0 = it << 4;
#pragma unroll
    for (int g = 0; g < 16; ++g) {
      float v = partL[g];
      v += __shfl_xor(v, 1); v += __shfl_xor(v, 2);
      v += __shfl_xor(v, 4); v += __shfl_xor(v, 8);
      if (m == 0)
        atomicAdd(&Lbuf[(((size_t)(b << 10) + i0 + (w << 2) + quad) << 4) + g], v);
    }
  }
}

// ---- pass 2: recompute, normalize, W_post per column, PV with v[g2] --------
__global__ __launch_bounds__(256)
void attn_pv2(const unsigned short* __restrict__ qb, const unsigned short* __restrict__ kall,
              const unsigned short* __restrict__ vallT, const float* __restrict__ W_pre,
              const float* __restrict__ W_post, const float* __restrict__ Lbuf,
              float* __restrict__ Obuf)
{
  __shared__ float sS[16 * 16 * 32];            // [h][i][j 0..31], swizzled cols
  __shared__ __align__(16) unsigned short sE[16 * 16 * 32]; // bf16 p2, granule-swizzled
  __shared__ f32x4 sWpre4[64], sWpost4[64];
  __shared__ float sIL[256];

  const int t = threadIdx.x, lane = t & 63, w = t >> 6;
  const int m = lane & 15, quad = lane >> 4;
  if (t < 64) {
    int h = t >> 2, p4 = t & 3;
    sWpre4[t]  = (f32x4){W_pre[(4 * p4 + 0) * 16 + h],  W_pre[(4 * p4 + 1) * 16 + h],
                         W_pre[(4 * p4 + 2) * 16 + h],  W_pre[(4 * p4 + 3) * 16 + h]};
    sWpost4[t] = (f32x4){W_post[(4 * p4 + 0) * 16 + h], W_post[(4 * p4 + 1) * 16 + h],
                         W_post[(4 * p4 + 2) * 16 + h], W_post[(4 * p4 + 3) * 16 + h]};
  }

  const int blk = blockIdx.x;                   // grid 768
  const int u0 = (4352 * blk) / 768, u1 = (4352 * (blk + 1)) / 768;
  if (u0 == u1) return;

  int accu = 0, bi = 0;
  while (true) {
    int un = (((bi & 63) + 1) >> 1) + 1;
    if (accu + un > u0) break;
    accu += un; ++bi;
  }
  int b = bi >> 6, it = bi & 63, uoff = u0 - accu;

  short8 afr[4][2];
  f32x4 oacc[4][4];
  bool fresh = true;

  for (int u = u0; u < u1; ++u) {
    const int i0 = it << 4;
    if (fresh) {
#pragma unroll
      for (int hh = 0; hh < 4; ++hh)
#pragma unroll
        for (int kk = 0; kk < 2; ++kk)
          afr[hh][kk] = *(const short8*)(qb + (((size_t)(b << 10) + i0 + m) << 10)
                                         + ((w << 2) + hh) * 64 + kk * 32 + quad * 8);
#pragma unroll
      for (int a = 0; a < 4; ++a)
#pragma unroll
        for (int dt = 0; dt < 4; ++dt) oacc[a][dt] = (f32x4){0.f, 0.f, 0.f, 0.f};
      sIL[t] = 1.f / Lbuf[(((size_t)(b << 10) + i0 + (t >> 4)) << 4) + (t & 15)];
      fresh = false;
    }
    const int j0 = uoff << 5;
    // ---- QK: both 16-j subtiles -> sS ----
#pragma unroll
    for (int sub = 0; sub < 2; ++sub) {
      const int js = j0 + (sub << 4);
#pragma unroll
      for (int hh = 0; hh < 4; ++hh) {
        f32x4 s = (f32x4){0.f, 0.f, 0.f, 0.f};
#pragma unroll
        for (int kk = 0; kk < 2; ++kk) {
          short8 bfr = *(const short8*)(kall + ((size_t)(b * 1056 + js + m) << 10)
                                        + ((w << 2) + hh) * 64 + kk * 32 + quad * 8);
          s = __builtin_amdgcn_mfma_f32_16x16x32_bf16(afr[hh][kk], bfr, s, 0, 0, 0);
        }
#pragma unroll
        for (int reg = 0; reg < 4; ++reg) {
          int irow = (quad << 2) + reg;
          sS[(((w << 2) + hh) * 16 + irow) * 32 + (((sub << 4) + m) ^ SWZS(irow))] = s[reg];
        }
      }
    }
    __syncthreads();   // also covers sIL write at fresh
    // ---- packed premix + exp + normalize + packed W_post -> p2 bf16 ----
    {
      const int i_l = t >> 4, j_l = t & 15;
      const int ig = i0 + i_l;
      const int vs = SWZS(i_l);
      const int sc0 = j_l ^ vs, sc1 = (16 + j_l) ^ vs;
      const int r3s = i_l & 3;
      const int eo0 = ((((j_l >> 3) ^ r3s) << 3) | (j_l & 7));
      const int eo1 = ((((2 + (j_l >> 3)) ^ r3s) << 3) | (j_l & 7));
      float ch0[16], ch1[16];
#pragma unroll
      for (int h = 0; h < 16; ++h) {
        ch0[h] = sS[(h * 16 + i_l) * 32 + sc0];
        ch1[h] = sS[(h * 16 + i_l) * 32 + sc1];
      }
      f32x4 a0[4], a1[4];
#pragma unroll
      for (int p = 0; p < 4; ++p) { a0[p] = (f32x4){0.f,0.f,0.f,0.f}; a1[p] = a0[p]; }
#pragma unroll
      for (int h = 0; h < 16; ++h) {
        float c0 = ch0[h], c1 = ch1[h];
#pragma unroll
        for (int p = 0; p < 4; ++p) {
          f32x4 wv = sWpre4[(h << 2) + p];
          a0[p] += wv * c0;
          a1[p] += wv * c1;
        }
      }
      const bool ok0 = (j0 + j_l) <= ig + 16;
      const bool ok1 = (j0 + 16 + j_l) <= ig + 16;
      float e0[16], e1[16];
#pragma unroll
      for (int p = 0; p < 4; ++p)
#pragma unroll
        for (int e = 0; e < 4; ++e) {
          int g = (p << 2) + e;
          float il = sIL[(i_l << 4) + g];
          e0[g] = ok0 ? __expf(a0[p][e] - 20.f) * il : 0.f;
          e1[g] = ok1 ? __expf(a1[p][e] - 20.f) * il : 0.f;
        }
      f32x4 b0[4], b1[4];
#pragma unroll
      for (int p = 0; p < 4; ++p) { b0[p] = (f32x4){0.f,0.f,0.f,0.f}; b1[p] = b0[p]; }
#pragma unroll
      for (int g = 0; g < 16; ++g) {
        float c0 = e0[g], c1 = e1[g];
#pragma unroll
        for (int p = 0; p < 4; ++p) {
          f32x4 wv = sWpost4[(g << 2) + p];
          b0[p] += wv * c0;
          b1[p] += wv * c1;
        }
      }
#pragma unroll
      for (int p = 0; p < 4; ++p)
#pragma unroll
        for (int e = 0; e < 4; ++e) {
          int g2 = (p << 2) + e;
          sE[(g2 * 16 + i_l) * 32 + eo0] = to_bf(b0[p][e]);
          sE[(g2 * 16 + i_l) * 32 + eo1] = to_bf(b1[p][e]);
        }
    }
    __syncthreads();
    // ---- PV: wave w owns g2 = 4w..4w+3; V indexed by g2 (output head) ----
#pragma unroll
    for (int gl = 0; gl < 4; ++gl) {
      const int g2 = (w << 2) + gl;
      short8 a = *(const short8*)(sE + (g2 * 16 + m) * 32 + ((quad ^ (m & 3)) << 3));
#pragma unroll
      for (int dt = 0; dt < 4; ++dt) {
        short8 bv = *(const short8*)(vallT + ((size_t)((b << 10) + g2 * 64 + dt * 16 + m)) * 1056
                                     + j0 + quad * 8);
        oacc[gl][dt] = __builtin_amdgcn_mfma_f32_16x16x32_bf16(a, bv, oacc[gl][dt], 0, 0, 0);
      }
    }
    ++uoff;
    if (uoff == ((it + 1) >> 1) + 1) {
#pragma unroll
      for (int gl = 0; gl < 4; ++gl) {
        int g2 = (w << 2) + gl;
#pragma unroll
        for (int dt = 0; dt < 4; ++dt)
#pragma unroll
          for (int reg = 0; reg < 4; ++reg)
            atomicAdd(&Obuf[(((size_t)(b << 10) + i0 + (quad << 2) + reg) << 10)
                            + g2 * 64 + dt * 16 + m], oacc[gl][dt][reg]);
      }
      ++bi; b = bi >> 6; it = bi & 63; uoff = 0; fresh = true;
    }
  }
  if (!fresh) {
    const int i0 = it << 4;
#pragma unroll
    for (int gl = 0; gl < 4; ++gl) {
      int g2 = (w << 2) + gl;
#pragma unroll
      for (int dt = 0; dt < 4; ++dt)
#pragma unroll
        for (int reg = 0; reg < 4; ++reg)
          atomicAdd(&Obuf[(((size_t)(b << 10) + i0 + (quad << 2) + reg) << 10)
                          + g2 * 64 + dt * 16 + m], oacc[gl][dt][reg]);
    }
  }
}

// ---- epilogue: aob = Obuf * hgate * vgate (bf16) ---------------------------
__global__ __launch_bounds__(256)
void gate_out(const float* __restrict__ Obuf, const float* __restrict__ hgate,
              const float* __restrict__ vgate, unsigned short* __restrict__ aob)
{
  int i4 = blockIdx.x * 256 + threadIdx.x;   // 1048576 float4 groups
  float4 o = ((const float4*)Obuf)[i4];
  int base = i4 << 2;
  int row = base >> 10, hd = base & 1023, h = hd >> 6;
  float hg = hgate[(row << 4) + h];
  float4 vg = ((const float4*)vgate)[i4];
  ushort4 r;
  r.x = to_bf(o.x * hg * vg.x);
  r.y = to_bf(o.y * hg * vg.y);
  r.z = to_bf(o.z * hg * vg.z);
  r.w = to_bf(o.w * hg * vg.w);
  ((ushort4*)aob)[i4] = r;
}

extern "C" void kernel_launch(void* const* d_in, const int* in_sizes, int n_in,
                              void* d_out, int out_size, void* d_ws, size_t ws_size,
                              hipStream_t stream)
{
  const float* x       = (const float*)d_in[0];
  const float* freqs   = (const float*)d_in[1];
  const float* Wq      = (const float*)d_in[2];
  const float* Wk      = (const float*)d_in[3];
  const float* Wv      = (const float*)d_in[4];
  const float* q_scale = (const float*)d_in[5];
  const float* k_scale = (const float*)d_in[6];
  const float* mem_k   = (const float*)d_in[7];
  const float* mem_v   = (const float*)d_in[8];
  const float* W_pre   = (const float*)d_in[9];
  const float* W_post  = (const float*)d_in[10];
  const float* W_hg    = (const float*)d_in[11];
  const float* b_hg    = (const float*)d_in[12];
  const float* W_vg    = (const float*)d_in[13];
  const float* b_vg    = (const float*)d_in[14];
  const float* Wo      = (const float*)d_in[15];
  float* out = (float*)d_out;
  float* ws  = (float*)d_ws;

  // workspace (float offsets), non-overlapping; total 19,660,800 f = 78.6 MiB
  float* q_lin = ws;                                        // [4096,1024]; dead -> aob+Lbuf
  unsigned short* aob = (unsigned short*)ws;                // [0 .. 2,097,152) floats-worth
  float* Lbuf  = ws + 4128768;                              // [4,1024,16] (q_lin tail, after aob)
  float* k_lin = ws + 4194304;                              // [4096,1024]; dead -> Obuf
  float* Obuf  = k_lin;                                     // [4,1024,16,64] fp32
  float* vgbuf = ws + 8388608;                              // [4096,1024]
  float* hgbuf = ws + 12582912;                             // [4096,16]
  unsigned short* xb   = (unsigned short*)(ws + 12713984);  // [4096,1024] bf16 -> qb
  unsigned short* qb   = xb;                                // ends 14,811,136
  unsigned short* kall = (unsigned short*)(ws + 14811136);  // [4,1056,1024] bf16; ends 16,973,824
  unsigned short* vallT= (unsigned short*)(ws + 16973824);  // [4,1024,1056] bf16; ends 19,136,512
  // wb4 [4096,1024] bf16 ALIASES kall (+pad): fully consumed by gemm_qkvg
  // before k_post/mem_build overwrite the region (stream-serial). Wo's wb
  // reuses the same region after attn_pv2 (kall dead by then).
  unsigned short* wb4  = kall;

  dim3 blk(256);
  cvt_bf16x4<<<4096, blk, 0, stream>>>(x, xb, 1048576);
  // fused head-gate projection (fp32, reads original x)
  hgate_proj<<<256, blk, 0, stream>>>(x, W_hg, b_hg, hgbuf);
  // fused QKVG projection: one transpose batch + one 4096x4096x1024 GEMM
  transpose4_to_bf<<<dim3(16, 16, 4), blk, 0, stream>>>(Wq, Wk, Wv, W_vg, wb4);
  gemm_qkvg<<<dim3(64, 32), blk, 0, stream>>>(xb, wb4, q_lin, k_lin, vallT, vgbuf, b_vg);
  // q/k/mem postprocessing (qb overwrites xb; kall overwrites wb4 -- both dead)
  q_post_bf<<<16384, blk, 0, stream>>>(q_lin, q_scale, freqs, qb);
  k_post_bf<<<16384, blk, 0, stream>>>(k_lin, k_scale, freqs, kall);
  mem_build<<<64, blk, 0, stream>>>(mem_k, mem_v, k_scale, kall, vallT);
  // zero Lbuf+Obuf in ONE contiguous memset (q_lin/k_lin dead by now)
  hipMemsetAsync(Lbuf, 0, (65536 + 4194304) * sizeof(float), stream);
  // two-pass attention + gate epilogue
  attn_lsum<<<768, blk, 0, stream>>>(qb, kall, W_pre, Lbuf);
  attn_pv2<<<768, blk, 0, stream>>>(qb, kall, vallT, W_pre, W_post, Lbuf, Obuf);
  gate_out<<<4096, blk, 0, stream>>>(Obuf, hgbuf, vgbuf, aob);
  // output projection (wb reuses the kall region -- attention done)
  transpose_to_bf<<<dim3(16, 16), blk, 0, stream>>>(Wo, wb4);
  gemm_bf128<<<dim3(16, 32), blk, 0, stream>>>(aob, wb4, out);
}

// Round 11
// 484.949 us; speedup vs baseline: 1.0615x; 1.0615x over previous
//
#include <hip/hip_runtime.h>
#include <hip/hip_bf16.h>
#include <cmath>

// B=4, N=1024, DIM=1024, H=16, DH=64, M=16, QK_SCALE=10
typedef __attribute__((ext_vector_type(8))) short short8;
typedef __attribute__((ext_vector_type(4))) float f32x4;

__device__ __forceinline__ unsigned short to_bf(float f) {
  __hip_bfloat16 h = __float2bfloat16(f);
  return __builtin_bit_cast(unsigned short, h);
}

// sS row-col XOR swizzle: spreads the 4 i-rows of a wave across both 16-bank
// halves -> QK 4B stores and premix 4B reads are 2-way (free) instead of 4-way.
#define SWZS(ir) ((((ir) & 1) << 4) | (((ir) & 6) << 1))

// -------- fp32 -> bf16 elementwise ------------------------------------------
__global__ __launch_bounds__(256)
void cvt_bf16x4(const float* __restrict__ in, unsigned short* __restrict__ out, int n4)
{
  int i = blockIdx.x * 256 + threadIdx.x;
  if (i < n4) {
    float4 v = ((const float4*)in)[i];
    ushort4 o;
    o.x = to_bf(v.x); o.y = to_bf(v.y); o.z = to_bf(v.z); o.w = to_bf(v.w);
    ((ushort4*)out)[i] = o;
  }
}

// -------- W [1024 k][1024 n] fp32 -> WT [n][k] bf16 -------------------------
__global__ __launch_bounds__(256)
void transpose_to_bf(const float* __restrict__ W, unsigned short* __restrict__ WT)
{
  __shared__ float tile[64][65];
  const int n0 = blockIdx.x * 64, k0 = blockIdx.y * 64;
  const int t = threadIdx.x, c = t & 63, r4 = t >> 6;
#pragma unroll
  for (int q = 0; q < 16; ++q) {
    int r = (q << 2) + r4;
    tile[r][c] = W[(size_t)(k0 + r) * 1024 + n0 + c];
  }
  __syncthreads();
#pragma unroll
  for (int q = 0; q < 16; ++q) {
    int r = (q << 2) + r4;
    WT[(size_t)(n0 + r) * 1024 + k0 + c] = to_bf(tile[c][r]);
  }
}

// -------- 4 weights -> one WT4 [4096 n][1024 k] bf16 (z = weight) -----------
__global__ __launch_bounds__(256)
void transpose4_to_bf(const float* __restrict__ W0, const float* __restrict__ W1,
                      const float* __restrict__ W2, const float* __restrict__ W3,
                      unsigned short* __restrict__ WT4)
{
  __shared__ float tile[64][65];
  const float* W = (blockIdx.z == 0) ? W0 : (blockIdx.z == 1) ? W1
                 : (blockIdx.z == 2) ? W2 : W3;
  const int n0 = blockIdx.x * 64, k0 = blockIdx.y * 64;
  const int t = threadIdx.x, c = t & 63, r4 = t >> 6;
#pragma unroll
  for (int q = 0; q < 16; ++q) {
    int r = (q << 2) + r4;
    tile[r][c] = W[(size_t)(k0 + r) * 1024 + n0 + c];
  }
  __syncthreads();
  const size_t zoff = (size_t)blockIdx.z << 10;
#pragma unroll
  for (int q = 0; q < 16; ++q) {
    int r = (q << 2) + r4;
    WT4[(zoff + n0 + r) * 1024 + k0 + c] = to_bf(tile[c][r]);
  }
}

// ---- bf16 MFMA GEMM, 128x64 tile, BK=32, stride-72 LDS (R9-proven form) ----
__global__ __launch_bounds__(256)
void gemm_bf128(const unsigned short* __restrict__ A, const unsigned short* __restrict__ BT,
                float* __restrict__ C)
{
  __shared__ __align__(16) unsigned short Ab[128 * 36];
  __shared__ __align__(16) unsigned short Bb[64 * 36];
  const int t = threadIdx.x, lane = t & 63, w = t >> 6;
  const int m = lane & 15, quad = lane >> 4;
  const int row0 = blockIdx.y << 7, col0 = blockIdx.x << 6;

  const int r0 = t >> 2, kp0 = t & 3;
  const int r1 = 64 + r0;

  f32x4 acc[2][4];
#pragma unroll
  for (int mi = 0; mi < 2; ++mi)
#pragma unroll
    for (int ni = 0; ni < 4; ++ni) acc[mi][ni] = (f32x4){0.f, 0.f, 0.f, 0.f};

  uint4 pa0 = *(const uint4*)(A + (size_t)(row0 + r0) * 1024 + kp0 * 8);
  uint4 pa1 = *(const uint4*)(A + (size_t)(row0 + r1) * 1024 + kp0 * 8);
  uint4 pb0 = *(const uint4*)(BT + (size_t)(col0 + r0) * 1024 + kp0 * 8);

  for (int kk = 0; kk < 1024; kk += 32) {
    *(uint4*)((char*)Ab + r0 * 72 + kp0 * 16) = pa0;
    *(uint4*)((char*)Ab + r1 * 72 + kp0 * 16) = pa1;
    *(uint4*)((char*)Bb + r0 * 72 + kp0 * 16) = pb0;
    __syncthreads();
    if (kk + 32 < 1024) {
      pa0 = *(const uint4*)(A + (size_t)(row0 + r0) * 1024 + kk + 32 + kp0 * 8);
      pa1 = *(const uint4*)(A + (size_t)(row0 + r1) * 1024 + kk + 32 + kp0 * 8);
      pb0 = *(const uint4*)(BT + (size_t)(col0 + r0) * 1024 + kk + 32 + kp0 * 8);
    }
    short8 af[2], bf[4];
#pragma unroll
    for (int mi = 0; mi < 2; ++mi)
      af[mi] = *(const short8*)((char*)Ab + ((w << 5) + (mi << 4) + m) * 72 + quad * 16);
#pragma unroll
    for (int ni = 0; ni < 4; ++ni)
      bf[ni] = *(const short8*)((char*)Bb + ((ni << 4) + m) * 72 + quad * 16);
#pragma unroll
    for (int mi = 0; mi < 2; ++mi)
#pragma unroll
      for (int ni = 0; ni < 4; ++ni)
        acc[mi][ni] = __builtin_amdgcn_mfma_f32_16x16x32_bf16(af[mi], bf[ni], acc[mi][ni], 0, 0, 0);
    __syncthreads();
  }
#pragma unroll
  for (int mi = 0; mi < 2; ++mi)
#pragma unroll
    for (int ni = 0; ni < 4; ++ni)
#pragma unroll
      for (int reg = 0; reg < 4; ++reg) {
        int mrow = row0 + (w << 5) + (mi << 4) + (quad << 2) + reg;
        int ncol = col0 + (ni << 4) + m;
        C[((size_t)mrow << 10) + ncol] = acc[mi][ni][reg];
      }
}

// ---- fused QKVG GEMM + q/k postprocess -------------------------------------
// R17: sectors 0/1 fuse l2norm+scale+rope (+x10 for q) in-register and write
// qb / kall bf16 directly -- eliminates q_post/k_post kernels and the fp32
// q_lin/k_lin intermediates. Geometry: a sector-0/1 block's 64 cols = ONE
// head's d-range; per output row the 64 d live in 4 ni-slots x 16 m-lanes ->
// l2norm = in-thread squares + shfl_xor(1,2,4,8); rope pair d^1 = lane^1.
// sector 2 = vallT bf16 (V^T), sector 3 = vgbuf sigmoid(.+b_vg).
__global__ __launch_bounds__(256)
void gemm_qkvg(const unsigned short* __restrict__ A, const unsigned short* __restrict__ BT4,
               const float* __restrict__ q_scale, const float* __restrict__ k_scale,
               const float* __restrict__ freqs,
               unsigned short* __restrict__ qb, unsigned short* __restrict__ kall,
               unsigned short* __restrict__ vallT, float* __restrict__ vgbuf,
               const float* __restrict__ b_vg)
{
  __shared__ __align__(16) unsigned short Ab[128 * 36];
  __shared__ __align__(16) unsigned short Bb[64 * 36];
  const int t = threadIdx.x, lane = t & 63, w = t >> 6;
  const int m = lane & 15, quad = lane >> 4;
  const int row0 = blockIdx.y << 7, col0 = blockIdx.x << 6;
  const int sector = col0 >> 10;

  const int r0 = t >> 2, kp0 = t & 3;
  const int r1 = 64 + r0;

  f32x4 acc[2][4];
#pragma unroll
  for (int mi = 0; mi < 2; ++mi)
#pragma unroll
    for (int ni = 0; ni < 4; ++ni) acc[mi][ni] = (f32x4){0.f, 0.f, 0.f, 0.f};

  uint4 pa0 = *(const uint4*)(A + (size_t)(row0 + r0) * 1024 + kp0 * 8);
  uint4 pa1 = *(const uint4*)(A + (size_t)(row0 + r1) * 1024 + kp0 * 8);
  uint4 pb0 = *(const uint4*)(BT4 + (size_t)(col0 + r0) * 1024 + kp0 * 8);

  for (int kk = 0; kk < 1024; kk += 32) {
    *(uint4*)((char*)Ab + r0 * 72 + kp0 * 16) = pa0;
    *(uint4*)((char*)Ab + r1 * 72 + kp0 * 16) = pa1;
    *(uint4*)((char*)Bb + r0 * 72 + kp0 * 16) = pb0;
    __syncthreads();
    if (kk + 32 < 1024) {
      pa0 = *(const uint4*)(A + (size_t)(row0 + r0) * 1024 + kk + 32 + kp0 * 8);
      pa1 = *(const uint4*)(A + (size_t)(row0 + r1) * 1024 + kk + 32 + kp0 * 8);
      pb0 = *(const uint4*)(BT4 + (size_t)(col0 + r0) * 1024 + kk + 32 + kp0 * 8);
    }
    short8 af[2], bf[4];
#pragma unroll
    for (int mi = 0; mi < 2; ++mi)
      af[mi] = *(const short8*)((char*)Ab + ((w << 5) + (mi << 4) + m) * 72 + quad * 16);
#pragma unroll
    for (int ni = 0; ni < 4; ++ni)
      bf[ni] = *(const short8*)((char*)Bb + ((ni << 4) + m) * 72 + quad * 16);
#pragma unroll
    for (int mi = 0; mi < 2; ++mi)
#pragma unroll
      for (int ni = 0; ni < 4; ++ni)
        acc[mi][ni] = __builtin_amdgcn_mfma_f32_16x16x32_bf16(af[mi], bf[ni], acc[mi][ni], 0, 0, 0);
    __syncthreads();
  }
  // C/D layout: col = lane&15, row = quad*4 + reg
  if (sector <= 1) {
    // ---- fused l2norm * scale * rope (+QK_SCALE for q) -> bf16 ----
    const float* scale = (sector == 0) ? q_scale : k_scale;
    const float mulf = (sector == 0) ? 10.f : 1.f;
    const int h6 = col0 & 1023;        // h*64
#pragma unroll
    for (int mi = 0; mi < 2; ++mi)
#pragma unroll
      for (int reg = 0; reg < 4; ++reg) {
        float ss = 0.f;
#pragma unroll
        for (int ni = 0; ni < 4; ++ni) {
          float v = acc[mi][ni][reg];
          ss += v * v;
        }
        ss += __shfl_xor(ss, 1); ss += __shfl_xor(ss, 2);
        ss += __shfl_xor(ss, 4); ss += __shfl_xor(ss, 8);
        const float inv = 1.f / fmaxf(sqrtf(ss), 1e-12f);
        const int mrow = row0 + (w << 5) + (mi << 4) + (quad << 2) + reg;
        const int n = mrow & 1023, b = mrow >> 10;
#pragma unroll
        for (int ni = 0; ni < 4; ++ni) {
          int d = (ni << 4) + m;
          float vn = acc[mi][ni][reg] * inv * scale[h6 + d];
          float other = __shfl_xor(vn, 1);
          float rot = (d & 1) ? other : -other;
          float f = freqs[(n << 6) + d];
          float o = (vn * __cosf(f) + rot * __sinf(f)) * mulf;
          if (sector == 0)
            qb[((size_t)mrow << 10) + h6 + d] = to_bf(o);
          else
            kall[(size_t)(b * 1056 + 16 + n) * 1024 + h6 + d] = to_bf(o);
        }
      }
  } else {
#pragma unroll
    for (int mi = 0; mi < 2; ++mi)
#pragma unroll
      for (int ni = 0; ni < 4; ++ni)
#pragma unroll
        for (int reg = 0; reg < 4; ++reg) {
          int mrow = row0 + (w << 5) + (mi << 4) + (quad << 2) + reg;
          int nl = (col0 & 1023) + (ni << 4) + m;
          float v = acc[mi][ni][reg];
          if (sector == 2) {
            int bb = mrow >> 10, nn = mrow & 1023;
            vallT[((size_t)((bb << 10) + nl)) * 1056 + 16 + nn] = to_bf(v);
          } else {
            float s = v + b_vg[nl];
            vgbuf[((size_t)mrow << 10) + nl] = 1.f / (1.f + __expf(-s));
          }
        }
  }
}

// ---- fused head-gate projection: hg = sigmoid(x @ W_hg + b_hg) -------------
__global__ __launch_bounds__(256)
void hgate_proj(const float* __restrict__ x, const float* __restrict__ W,
                const float* __restrict__ bias, float* __restrict__ hg)
{
  int G = blockIdx.x * 256 + threadIdx.x;
  int row = G >> 4, h = G & 15;
  const float4* x4 = (const float4*)(x + ((size_t)row << 10));
  float acc = 0.f;
#pragma unroll 4
  for (int k4 = 0; k4 < 256; ++k4) {
    float4 xv = x4[k4];
    int kb = k4 << 2;
    acc += xv.x * W[(kb + 0) * 16 + h] + xv.y * W[(kb + 1) * 16 + h]
         + xv.z * W[(kb + 2) * 16 + h] + xv.w * W[(kb + 3) * 16 + h];
  }
  float v = acc + bias[h];
  hg[(row << 4) + h] = 1.f / (1.f + __expf(-v));
}

// ------ memory slots into kall rows 0..15 and vallT cols 0..15 --------------
__global__ __launch_bounds__(256)
void mem_build(const float* __restrict__ mem_k, const float* __restrict__ mem_v,
               const float* __restrict__ k_scale,
               unsigned short* __restrict__ kall, unsigned short* __restrict__ vallT)
{
  int gid = blockIdx.x * 256 + threadIdx.x;   // 16384 = H*M*64
  int d = gid & 63;
  int row = gid >> 6;            // h*M + mm
  int h = row >> 4, mm = row & 15;
  float v = mem_k[gid];
  float ss = v * v;
#pragma unroll
  for (int off = 32; off; off >>= 1) ss += __shfl_xor(ss, off);
  unsigned short kb = to_bf(v / fmaxf(sqrtf(ss), 1e-12f) * k_scale[(h << 6) + d]);
  unsigned short vb = to_bf(mem_v[gid]);
#pragma unroll
  for (int b = 0; b < 4; ++b) {
    kall[(size_t)(b * 1056 + mm) * 1024 + (h << 6) + d] = kb;
    vallT[(size_t)((b << 10) + (h << 6) + d) * 1056 + mm] = vb;
  }
}

// ================= two-pass MFMA attention, flat-balanced ===================
// Attention = R7-proven best (pv2 natural alloc 168 VGPR, 158.5 us; grid 768).
// Hardened: R1/R5 pins spilled, R8 restructure spilled -- do not touch.

// ---- pass 1: denominators L[b][i][g] via atomicAdd -------------------------
__global__ __launch_bounds__(256)
void attn_lsum(const unsigned short* __restrict__ qb, const unsigned short* __restrict__ kall,
               const float* __restrict__ W_pre, float* __restrict__ Lbuf)
{
  __shared__ float sS[16 * 16 * 32];            // [h][i][j 0..31], swizzled cols
  __shared__ f32x4 sWpre4[64];

  const int t = threadIdx.x, lane = t & 63, w = t >> 6;
  const int m = lane & 15, quad = lane >> 4;
  if (t < 64) {
    int h = t >> 2, p4 = t & 3;
    sWpre4[t] = (f32x4){W_pre[(4 * p4 + 0) * 16 + h], W_pre[(4 * p4 + 1) * 16 + h],
                        W_pre[(4 * p4 + 2) * 16 + h], W_pre[(4 * p4 + 3) * 16 + h]};
  }

  const int blk = blockIdx.x;                   // grid 768
  const int u0 = (4352 * blk) / 768, u1 = (4352 * (blk + 1)) / 768;
  if (u0 == u1) return;

  int accu = 0, bi = 0;
  while (true) {
    int un = (((bi & 63) + 1) >> 1) + 1;
    if (accu + un > u0) break;
    accu += un; ++bi;
  }
  int b = bi >> 6, it = bi & 63, uoff = u0 - accu;

  short8 afr[4][2];
  float partL[16];
  bool fresh = true;

  for (int u = u0; u < u1; ++u) {
    const int i0 = it << 4;
    if (fresh) {
#pragma unroll
      for (int hh = 0; hh < 4; ++hh)
#pragma unroll
        for (int kk = 0; kk < 2; ++kk)
          afr[hh][kk] = *(const short8*)(qb + (((size_t)(b << 10) + i0 + m) << 10)
                                         + ((w << 2) + hh) * 64 + kk * 32 + quad * 8);
#pragma unroll
      for (int g = 0; g < 16; ++g) partL[g] = 0.f;
      fresh = false;
    }
    const int j0 = uoff << 5;
    // ---- QK: both 16-j subtiles -> sS ----
#pragma unroll
    for (int sub = 0; sub < 2; ++sub) {
      const int js = j0 + (sub << 4);
#pragma unroll
      for (int hh = 0; hh < 4; ++hh) {
        f32x4 s = (f32x4){0.f, 0.f, 0.f, 0.f};
#pragma unroll
        for (int kk = 0; kk < 2; ++kk) {
          short8 bfr = *(const short8*)(kall + ((size_t)(b * 1056 + js + m) << 10)
                                        + ((w << 2) + hh) * 64 + kk * 32 + quad * 8);
          s = __builtin_amdgcn_mfma_f32_16x16x32_bf16(afr[hh][kk], bfr, s, 0, 0, 0);
        }
#pragma unroll
        for (int reg = 0; reg < 4; ++reg) {
          int irow = (quad << 2) + reg;
          sS[(((w << 2) + hh) * 16 + irow) * 32 + (((sub << 4) + m) ^ SWZS(irow))] = s[reg];
        }
      }
    }
    __syncthreads();
    // ---- packed premix + exp; 2 columns per thread ----
    {
      const int i_l = t >> 4, j_l = t & 15;
      const int ig = i0 + i_l;
      const int vs = SWZS(i_l);
      const int sc0 = j_l ^ vs, sc1 = (16 + j_l) ^ vs;
      float ch0[16], ch1[16];
#pragma unroll
      for (int h = 0; h < 16; ++h) {
        ch0[h] = sS[(h * 16 + i_l) * 32 + sc0];
        ch1[h] = sS[(h * 16 + i_l) * 32 + sc1];
      }
      f32x4 a0[4], a1[4];
#pragma unroll
      for (int p = 0; p < 4; ++p) { a0[p] = (f32x4){0.f,0.f,0.f,0.f}; a1[p] = a0[p]; }
#pragma unroll
      for (int h = 0; h < 16; ++h) {
        float c0 = ch0[h], c1 = ch1[h];
#pragma unroll
        for (int p = 0; p < 4; ++p) {
          f32x4 wv = sWpre4[(h << 2) + p];
          a0[p] += wv * c0;
          a1[p] += wv * c1;
        }
      }
      const bool ok0 = (j0 + j_l) <= ig + 16;
      const bool ok1 = (j0 + 16 + j_l) <= ig + 16;
#pragma unroll
      for (int p = 0; p < 4; ++p)
#pragma unroll
        for (int e = 0; e < 4; ++e) {
          float v0 = ok0 ? __expf(a0[p][e] - 20.f) : 0.f;
          float v1 = ok1 ? __expf(a1[p][e] - 20.f) : 0.f;
          partL[(p << 2) + e] += v0 + v1;
        }
    }
    __syncthreads();
    ++uoff;
    if (uoff == ((it + 1) >> 1) + 1) {
#pragma unroll
      for (int g = 0; g < 16; ++g) {
        float v = partL[g];
        v += __shfl_xor(v, 1); v += __shfl_xor(v, 2);
        v += __shfl_xor(v, 4); v += __shfl_xor(v, 8);
        if (m == 0)
          atomicAdd(&Lbuf[(((size_t)(b << 10) + i0 + (w << 2) + quad) << 4) + g], v);
      }
      ++bi; b = bi >> 6; it = bi & 63; uoff = 0; fresh = true;
    }
  }
  if (!fresh) {
    const int i0 = it << 4;
#pragma unroll
    for (int g = 0; g < 16; ++g) {
      float v = partL[g];
      v += __shfl_xor(v, 1); v += __shfl_xor(v, 2);
      v += __shfl_xor(v, 4); v += __shfl_xor(v, 8);
      if (m == 0)
        atomicAdd(&Lbuf[(((size_t)(b << 10) + i0 + (w << 2) + quad) << 4) + g], v);
    }
  }
}

// ---- pass 2: recompute, normalize, W_post per column, PV with v[g2] --------
__global__ __launch_bounds__(256)
void attn_pv2(const unsigned short* __restrict__ qb, const unsigned short* __restrict__ kall,
              const unsigned short* __restrict__ vallT, const float* __restrict__ W_pre,
              const float* __restrict__ W_post, const float* __restrict__ Lbuf,
              float* __restrict__ Obuf)
{
  __shared__ float sS[16 * 16 * 32];            // [h][i][j 0..31], swizzled cols
  __shared__ __align__(16) unsigned short sE[16 * 16 * 32]; // bf16 p2, granule-swizzled
  __shared__ f32x4 sWpre4[64], sWpost4[64];
  __shared__ float sIL[256];

  const int t = threadIdx.x, lane = t & 63, w = t >> 6;
  const int m = lane & 15, quad = lane >> 4;
  if (t < 64) {
    int h = t >> 2, p4 = t & 3;
    sWpre4[t]  = (f32x4){W_pre[(4 * p4 + 0) * 16 + h],  W_pre[(4 * p4 + 1) * 16 + h],
                         W_pre[(4 * p4 + 2) * 16 + h],  W_pre[(4 * p4 + 3) * 16 + h]};
    sWpost4[t] = (f32x4){W_post[(4 * p4 + 0) * 16 + h], W_post[(4 * p4 + 1) * 16 + h],
                         W_post[(4 * p4 + 2) * 16 + h], W_post[(4 * p4 + 3) * 16 + h]};
  }

  const int blk = blockIdx.x;                   // grid 768
  const int u0 = (4352 * blk) / 768, u1 = (4352 * (blk + 1)) / 768;
  if (u0 == u1) return;

  int accu = 0, bi = 0;
  while (true) {
    int un = (((bi & 63) + 1) >> 1) + 1;
    if (accu + un > u0) break;
    accu += un; ++bi;
  }
  int b = bi >> 6, it = bi & 63, uoff = u0 - accu;

  short8 afr[4][2];
  f32x4 oacc[4][4];
  bool fresh = true;

  for (int u = u0; u < u1; ++u) {
    const int i0 = it << 4;
    if (fresh) {
#pragma unroll
      for (int hh = 0; hh < 4; ++hh)
#pragma unroll
        for (int kk = 0; kk < 2; ++kk)
          afr[hh][kk] = *(const short8*)(qb + (((size_t)(b << 10) + i0 + m) << 10)
                                         + ((w << 2) + hh) * 64 + kk * 32 + quad * 8);
#pragma unroll
      for (int a = 0; a < 4; ++a)
#pragma unroll
        for (int dt = 0; dt < 4; ++dt) oacc[a][dt] = (f32x4){0.f, 0.f, 0.f, 0.f};
      sIL[t] = 1.f / Lbuf[(((size_t)(b << 10) + i0 + (t >> 4)) << 4) + (t & 15)];
      fresh = false;
    }
    const int j0 = uoff << 5;
    // ---- QK: both 16-j subtiles -> sS ----
#pragma unroll
    for (int sub = 0; sub < 2; ++sub) {
      const int js = j0 + (sub << 4);
#pragma unroll
      for (int hh = 0; hh < 4; ++hh) {
        f32x4 s = (f32x4){0.f, 0.f, 0.f, 0.f};
#pragma unroll
        for (int kk = 0; kk < 2; ++kk) {
          short8 bfr = *(const short8*)(kall + ((size_t)(b * 1056 + js + m) << 10)
                                        + ((w << 2) + hh) * 64 + kk * 32 + quad * 8);
          s = __builtin_amdgcn_mfma_f32_16x16x32_bf16(afr[hh][kk], bfr, s, 0, 0, 0);
        }
#pragma unroll
        for (int reg = 0; reg < 4; ++reg) {
          int irow = (quad << 2) + reg;
          sS[(((w << 2) + hh) * 16 + irow) * 32 + (((sub << 4) + m) ^ SWZS(irow))] = s[reg];
        }
      }
    }
    __syncthreads();   // also covers sIL write at fresh
    // ---- packed premix + exp + normalize + packed W_post -> p2 bf16 ----
    {
      const int i_l = t >> 4, j_l = t & 15;
      const int ig = i0 + i_l;
      const int vs = SWZS(i_l);
      const int sc0 = j_l ^ vs, sc1 = (16 + j_l) ^ vs;
      const int r3s = i_l & 3;
      const int eo0 = ((((j_l >> 3) ^ r3s) << 3) | (j_l & 7));
      const int eo1 = ((((2 + (j_l >> 3)) ^ r3s) << 3) | (j_l & 7));
      float ch0[16], ch1[16];
#pragma unroll
      for (int h = 0; h < 16; ++h) {
        ch0[h] = sS[(h * 16 + i_l) * 32 + sc0];
        ch1[h] = sS[(h * 16 + i_l) * 32 + sc1];
      }
      f32x4 a0[4], a1[4];
#pragma unroll
      for (int p = 0; p < 4; ++p) { a0[p] = (f32x4){0.f,0.f,0.f,0.f}; a1[p] = a0[p]; }
#pragma unroll
      for (int h = 0; h < 16; ++h) {
        float c0 = ch0[h], c1 = ch1[h];
#pragma unroll
        for (int p = 0; p < 4; ++p) {
          f32x4 wv = sWpre4[(h << 2) + p];
          a0[p] += wv * c0;
          a1[p] += wv * c1;
        }
      }
      const bool ok0 = (j0 + j_l) <= ig + 16;
      const bool ok1 = (j0 + 16 + j_l) <= ig + 16;
      float e0[16], e1[16];
#pragma unroll
      for (int p = 0; p < 4; ++p)
#pragma unroll
        for (int e = 0; e < 4; ++e) {
          int g = (p << 2) + e;
          float il = sIL[(i_l << 4) + g];
          e0[g] = ok0 ? __expf(a0[p][e] - 20.f) * il : 0.f;
          e1[g] = ok1 ? __expf(a1[p][e] - 20.f) * il : 0.f;
        }
      f32x4 b0[4], b1[4];
#pragma unroll
      for (int p = 0; p < 4; ++p) { b0[p] = (f32x4){0.f,0.f,0.f,0.f}; b1[p] = b0[p]; }
#pragma unroll
      for (int g = 0; g < 16; ++g) {
        float c0 = e0[g], c1 = e1[g];
#pragma unroll
        for (int p = 0; p < 4; ++p) {
          f32x4 wv = sWpost4[(g << 2) + p];
          b0[p] += wv * c0;
          b1[p] += wv * c1;
        }
      }
#pragma unroll
      for (int p = 0; p < 4; ++p)
#pragma unroll
        for (int e = 0; e < 4; ++e) {
          int g2 = (p << 2) + e;
          sE[(g2 * 16 + i_l) * 32 + eo0] = to_bf(b0[p][e]);
          sE[(g2 * 16 + i_l) * 32 + eo1] = to_bf(b1[p][e]);
        }
    }
    __syncthreads();
    // ---- PV: wave w owns g2 = 4w..4w+3; V indexed by g2 (output head) ----
#pragma unroll
    for (int gl = 0; gl < 4; ++gl) {
      const int g2 = (w << 2) + gl;
      short8 a = *(const short8*)(sE + (g2 * 16 + m) * 32 + ((quad ^ (m & 3)) << 3));
#pragma unroll
      for (int dt = 0; dt < 4; ++dt) {
        short8 bv = *(const short8*)(vallT + ((size_t)((b << 10) + g2 * 64 + dt * 16 + m)) * 1056
                                     + j0 + quad * 8);
        oacc[gl][dt] = __builtin_amdgcn_mfma_f32_16x16x32_bf16(a, bv, oacc[gl][dt], 0, 0, 0);
      }
    }
    ++uoff;
    if (uoff == ((it + 1) >> 1) + 1) {
#pragma unroll
      for (int gl = 0; gl < 4; ++gl) {
        int g2 = (w << 2) + gl;
#pragma unroll
        for (int dt = 0; dt < 4; ++dt)
#pragma unroll
          for (int reg = 0; reg < 4; ++reg)
            atomicAdd(&Obuf[(((size_t)(b << 10) + i0 + (quad << 2) + reg) << 10)
                            + g2 * 64 + dt * 16 + m], oacc[gl][dt][reg]);
      }
      ++bi; b = bi >> 6; it = bi & 63; uoff = 0; fresh = true;
    }
  }
  if (!fresh) {
    const int i0 = it << 4;
#pragma unroll
    for (int gl = 0; gl < 4; ++gl) {
      int g2 = (w << 2) + gl;
#pragma unroll
      for (int dt = 0; dt < 4; ++dt)
#pragma unroll
        for (int reg = 0; reg < 4; ++reg)
          atomicAdd(&Obuf[(((size_t)(b << 10) + i0 + (quad << 2) + reg) << 10)
                          + g2 * 64 + dt * 16 + m], oacc[gl][dt][reg]);
    }
  }
}

// ---- epilogue: aob = Obuf * hgate * vgate (bf16) ---------------------------
__global__ __launch_bounds__(256)
void gate_out(const float* __restrict__ Obuf, const float* __restrict__ hgate,
              const float* __restrict__ vgate, unsigned short* __restrict__ aob)
{
  int i4 = blockIdx.x * 256 + threadIdx.x;   // 1048576 float4 groups
  float4 o = ((const float4*)Obuf)[i4];
  int base = i4 << 2;
  int row = base >> 10, hd = base & 1023, h = hd >> 6;
  float hg = hgate[(row << 4) + h];
  float4 vg = ((const float4*)vgate)[i4];
  ushort4 r;
  r.x = to_bf(o.x * hg * vg.x);
  r.y = to_bf(o.y * hg * vg.y);
  r.z = to_bf(o.z * hg * vg.z);
  r.w = to_bf(o.w * hg * vg.w);
  ((ushort4*)aob)[i4] = r;
}

extern "C" void kernel_launch(void* const* d_in, const int* in_sizes, int n_in,
                              void* d_out, int out_size, void* d_ws, size_t ws_size,
                              hipStream_t stream)
{
  const float* x       = (const float*)d_in[0];
  const float* freqs   = (const float*)d_in[1];
  const float* Wq      = (const float*)d_in[2];
  const float* Wk      = (const float*)d_in[3];
  const float* Wv      = (const float*)d_in[4];
  const float* q_scale = (const float*)d_in[5];
  const float* k_scale = (const float*)d_in[6];
  const float* mem_k   = (const float*)d_in[7];
  const float* mem_v   = (const float*)d_in[8];
  const float* W_pre   = (const float*)d_in[9];
  const float* W_post  = (const float*)d_in[10];
  const float* W_hg    = (const float*)d_in[11];
  const float* b_hg    = (const float*)d_in[12];
  const float* W_vg    = (const float*)d_in[13];
  const float* b_vg    = (const float*)d_in[14];
  const float* Wo      = (const float*)d_in[15];
  float* out = (float*)d_out;
  float* ws  = (float*)d_ws;

  // workspace (float offsets), total 19,660,800 f = 78.6 MiB -- R17 remap:
  // wb4   [4096,1024] bf16 at 0 .. 2,097,152       (dead after gemm_qkvg)
  // qb    [4096,1024] bf16 at 2,097,152 .. 4,194,304 (written BY gemm_qkvg)
  // Obuf  [4,1024,16,64] f32 at 4,194,304 .. 8,388,608
  // vgbuf [4096,1024] f32 at 8,388,608 .. 12,582,912
  // hgbuf [4096,16]  f32 at 12,582,912 .. 12,648,448
  // Lbuf  [4,1024,16] f32 at 12,648,448 .. 12,713,984 (hgbuf-tail gap)
  // xb    [4096,1024] bf16 at 12,713,984 .. 14,811,136 (read-only during qkvg)
  // kall  [4,1056,1024] bf16 at 14,811,136 .. 16,973,824
  // vallT [4,1024,1056] bf16 at 16,973,824 .. 19,136,512
  // wbo   [1024,1024] bf16 at 19,136,512 .. 19,660,800 (Wo transpose)
  // aob   aliases ws+0 (wb4 dead by gate_out)
  unsigned short* wb4  = (unsigned short*)ws;
  unsigned short* qb   = (unsigned short*)(ws + 2097152);
  float* Obuf  = ws + 4194304;
  float* vgbuf = ws + 8388608;
  float* hgbuf = ws + 12582912;
  float* Lbuf  = ws + 12648448;
  unsigned short* xb    = (unsigned short*)(ws + 12713984);
  unsigned short* kall  = (unsigned short*)(ws + 14811136);
  unsigned short* vallT = (unsigned short*)(ws + 16973824);
  unsigned short* wbo   = (unsigned short*)(ws + 19136512);
  unsigned short* aob   = (unsigned short*)ws;

  dim3 blk(256);
  cvt_bf16x4<<<4096, blk, 0, stream>>>(x, xb, 1048576);
  // fused head-gate projection (fp32, reads original x)
  hgate_proj<<<256, blk, 0, stream>>>(x, W_hg, b_hg, hgbuf);
  // fused QKVG projection + q/k postprocess: one transpose batch + one GEMM
  transpose4_to_bf<<<dim3(16, 16, 4), blk, 0, stream>>>(Wq, Wk, Wv, W_vg, wb4);
  gemm_qkvg<<<dim3(64, 32), blk, 0, stream>>>(xb, wb4, q_scale, k_scale, freqs,
                                              qb, kall, vallT, vgbuf, b_vg);
  // memory slots (disjoint rows/cols of kall/vallT)
  mem_build<<<64, blk, 0, stream>>>(mem_k, mem_v, k_scale, kall, vallT);
  // zero Lbuf and Obuf (now non-contiguous -> two memsets)
  hipMemsetAsync(Lbuf, 0, 65536 * sizeof(float), stream);
  hipMemsetAsync(Obuf, 0, 4194304 * sizeof(float), stream);
  // two-pass attention + gate epilogue
  attn_lsum<<<768, blk, 0, stream>>>(qb, kall, W_pre, Lbuf);
  attn_pv2<<<768, blk, 0, stream>>>(qb, kall, vallT, W_pre, W_post, Lbuf, Obuf);
  gate_out<<<4096, blk, 0, stream>>>(Obuf, hgbuf, vgbuf, aob);
  // output projection
  transpose_to_bf<<<dim3(16, 16), blk, 0, stream>>>(Wo, wbo);
  gemm_bf128<<<dim3(16, 32), blk, 0, stream>>>(aob, wbo, out);
}

// Round 12
// 483.460 us; speedup vs baseline: 1.0648x; 1.0031x over previous
//
#include <hip/hip_runtime.h>
#include <hip/hip_bf16.h>
#include <cmath>

// B=4, N=1024, DIM=1024, H=16, DH=64, M=16, QK_SCALE=10
typedef __attribute__((ext_vector_type(8))) short short8;
typedef __attribute__((ext_vector_type(4))) float f32x4;

__device__ __forceinline__ unsigned short to_bf(float f) {
  __hip_bfloat16 h = __float2bfloat16(f);
  return __builtin_bit_cast(unsigned short, h);
}

// sS row-col XOR swizzle: spreads the 4 i-rows of a wave across both 16-bank
// halves -> QK 4B stores and premix 4B reads are 2-way (free) instead of 4-way.
#define SWZS(ir) ((((ir) & 1) << 4) | (((ir) & 6) << 1))

// -------- fp32 -> bf16 elementwise ------------------------------------------
__global__ __launch_bounds__(256)
void cvt_bf16x4(const float* __restrict__ in, unsigned short* __restrict__ out, int n4)
{
  int i = blockIdx.x * 256 + threadIdx.x;
  if (i < n4) {
    float4 v = ((const float4*)in)[i];
    ushort4 o;
    o.x = to_bf(v.x); o.y = to_bf(v.y); o.z = to_bf(v.z); o.w = to_bf(v.w);
    ((ushort4*)out)[i] = o;
  }
}

// -------- W [1024 k][1024 n] fp32 -> WT [n][k] bf16 -------------------------
__global__ __launch_bounds__(256)
void transpose_to_bf(const float* __restrict__ W, unsigned short* __restrict__ WT)
{
  __shared__ float tile[64][65];
  const int n0 = blockIdx.x * 64, k0 = blockIdx.y * 64;
  const int t = threadIdx.x, c = t & 63, r4 = t >> 6;
#pragma unroll
  for (int q = 0; q < 16; ++q) {
    int r = (q << 2) + r4;
    tile[r][c] = W[(size_t)(k0 + r) * 1024 + n0 + c];
  }
  __syncthreads();
#pragma unroll
  for (int q = 0; q < 16; ++q) {
    int r = (q << 2) + r4;
    WT[(size_t)(n0 + r) * 1024 + k0 + c] = to_bf(tile[c][r]);
  }
}

// -------- 4 weights -> one WT4 [4096 n][1024 k] bf16 (z = weight) -----------
__global__ __launch_bounds__(256)
void transpose4_to_bf(const float* __restrict__ W0, const float* __restrict__ W1,
                      const float* __restrict__ W2, const float* __restrict__ W3,
                      unsigned short* __restrict__ WT4)
{
  __shared__ float tile[64][65];
  const float* W = (blockIdx.z == 0) ? W0 : (blockIdx.z == 1) ? W1
                 : (blockIdx.z == 2) ? W2 : W3;
  const int n0 = blockIdx.x * 64, k0 = blockIdx.y * 64;
  const int t = threadIdx.x, c = t & 63, r4 = t >> 6;
#pragma unroll
  for (int q = 0; q < 16; ++q) {
    int r = (q << 2) + r4;
    tile[r][c] = W[(size_t)(k0 + r) * 1024 + n0 + c];
  }
  __syncthreads();
  const size_t zoff = (size_t)blockIdx.z << 10;
#pragma unroll
  for (int q = 0; q < 16; ++q) {
    int r = (q << 2) + r4;
    WT4[(zoff + n0 + r) * 1024 + k0 + c] = to_bf(tile[c][r]);
  }
}

// ---- bf16 MFMA GEMM, 128x64 tile, BK=32, stride-72 LDS (R9-proven form) ----
__global__ __launch_bounds__(256)
void gemm_bf128(const unsigned short* __restrict__ A, const unsigned short* __restrict__ BT,
                float* __restrict__ C)
{
  __shared__ __align__(16) unsigned short Ab[128 * 36];
  __shared__ __align__(16) unsigned short Bb[64 * 36];
  const int t = threadIdx.x, lane = t & 63, w = t >> 6;
  const int m = lane & 15, quad = lane >> 4;
  const int row0 = blockIdx.y << 7, col0 = blockIdx.x << 6;

  const int r0 = t >> 2, kp0 = t & 3;
  const int r1 = 64 + r0;

  f32x4 acc[2][4];
#pragma unroll
  for (int mi = 0; mi < 2; ++mi)
#pragma unroll
    for (int ni = 0; ni < 4; ++ni) acc[mi][ni] = (f32x4){0.f, 0.f, 0.f, 0.f};

  uint4 pa0 = *(const uint4*)(A + (size_t)(row0 + r0) * 1024 + kp0 * 8);
  uint4 pa1 = *(const uint4*)(A + (size_t)(row0 + r1) * 1024 + kp0 * 8);
  uint4 pb0 = *(const uint4*)(BT + (size_t)(col0 + r0) * 1024 + kp0 * 8);

  for (int kk = 0; kk < 1024; kk += 32) {
    *(uint4*)((char*)Ab + r0 * 72 + kp0 * 16) = pa0;
    *(uint4*)((char*)Ab + r1 * 72 + kp0 * 16) = pa1;
    *(uint4*)((char*)Bb + r0 * 72 + kp0 * 16) = pb0;
    __syncthreads();
    if (kk + 32 < 1024) {
      pa0 = *(const uint4*)(A + (size_t)(row0 + r0) * 1024 + kk + 32 + kp0 * 8);
      pa1 = *(const uint4*)(A + (size_t)(row0 + r1) * 1024 + kk + 32 + kp0 * 8);
      pb0 = *(const uint4*)(BT + (size_t)(col0 + r0) * 1024 + kk + 32 + kp0 * 8);
    }
    short8 af[2], bf[4];
#pragma unroll
    for (int mi = 0; mi < 2; ++mi)
      af[mi] = *(const short8*)((char*)Ab + ((w << 5) + (mi << 4) + m) * 72 + quad * 16);
#pragma unroll
    for (int ni = 0; ni < 4; ++ni)
      bf[ni] = *(const short8*)((char*)Bb + ((ni << 4) + m) * 72 + quad * 16);
#pragma unroll
    for (int mi = 0; mi < 2; ++mi)
#pragma unroll
      for (int ni = 0; ni < 4; ++ni)
        acc[mi][ni] = __builtin_amdgcn_mfma_f32_16x16x32_bf16(af[mi], bf[ni], acc[mi][ni], 0, 0, 0);
    __syncthreads();
  }
#pragma unroll
  for (int mi = 0; mi < 2; ++mi)
#pragma unroll
    for (int ni = 0; ni < 4; ++ni)
#pragma unroll
      for (int reg = 0; reg < 4; ++reg) {
        int mrow = row0 + (w << 5) + (mi << 4) + (quad << 2) + reg;
        int ncol = col0 + (ni << 4) + m;
        C[((size_t)mrow << 10) + ncol] = acc[mi][ni][reg];
      }
}

// ---- fused QKVG GEMM + q/k postprocess (R17-proven form) -------------------
__global__ __launch_bounds__(256)
void gemm_qkvg(const unsigned short* __restrict__ A, const unsigned short* __restrict__ BT4,
               const float* __restrict__ q_scale, const float* __restrict__ k_scale,
               const float* __restrict__ freqs,
               unsigned short* __restrict__ qb, unsigned short* __restrict__ kall,
               unsigned short* __restrict__ vallT, float* __restrict__ vgbuf,
               const float* __restrict__ b_vg)
{
  __shared__ __align__(16) unsigned short Ab[128 * 36];
  __shared__ __align__(16) unsigned short Bb[64 * 36];
  const int t = threadIdx.x, lane = t & 63, w = t >> 6;
  const int m = lane & 15, quad = lane >> 4;
  const int row0 = blockIdx.y << 7, col0 = blockIdx.x << 6;
  const int sector = col0 >> 10;

  const int r0 = t >> 2, kp0 = t & 3;
  const int r1 = 64 + r0;

  f32x4 acc[2][4];
#pragma unroll
  for (int mi = 0; mi < 2; ++mi)
#pragma unroll
    for (int ni = 0; ni < 4; ++ni) acc[mi][ni] = (f32x4){0.f, 0.f, 0.f, 0.f};

  uint4 pa0 = *(const uint4*)(A + (size_t)(row0 + r0) * 1024 + kp0 * 8);
  uint4 pa1 = *(const uint4*)(A + (size_t)(row0 + r1) * 1024 + kp0 * 8);
  uint4 pb0 = *(const uint4*)(BT4 + (size_t)(col0 + r0) * 1024 + kp0 * 8);

  for (int kk = 0; kk < 1024; kk += 32) {
    *(uint4*)((char*)Ab + r0 * 72 + kp0 * 16) = pa0;
    *(uint4*)((char*)Ab + r1 * 72 + kp0 * 16) = pa1;
    *(uint4*)((char*)Bb + r0 * 72 + kp0 * 16) = pb0;
    __syncthreads();
    if (kk + 32 < 1024) {
      pa0 = *(const uint4*)(A + (size_t)(row0 + r0) * 1024 + kk + 32 + kp0 * 8);
      pa1 = *(const uint4*)(A + (size_t)(row0 + r1) * 1024 + kk + 32 + kp0 * 8);
      pb0 = *(const uint4*)(BT4 + (size_t)(col0 + r0) * 1024 + kk + 32 + kp0 * 8);
    }
    short8 af[2], bf[4];
#pragma unroll
    for (int mi = 0; mi < 2; ++mi)
      af[mi] = *(const short8*)((char*)Ab + ((w << 5) + (mi << 4) + m) * 72 + quad * 16);
#pragma unroll
    for (int ni = 0; ni < 4; ++ni)
      bf[ni] = *(const short8*)((char*)Bb + ((ni << 4) + m) * 72 + quad * 16);
#pragma unroll
    for (int mi = 0; mi < 2; ++mi)
#pragma unroll
      for (int ni = 0; ni < 4; ++ni)
        acc[mi][ni] = __builtin_amdgcn_mfma_f32_16x16x32_bf16(af[mi], bf[ni], acc[mi][ni], 0, 0, 0);
    __syncthreads();
  }
  // C/D layout: col = lane&15, row = quad*4 + reg
  if (sector <= 1) {
    const float* scale = (sector == 0) ? q_scale : k_scale;
    const float mulf = (sector == 0) ? 10.f : 1.f;
    const int h6 = col0 & 1023;        // h*64
#pragma unroll
    for (int mi = 0; mi < 2; ++mi)
#pragma unroll
      for (int reg = 0; reg < 4; ++reg) {
        float ss = 0.f;
#pragma unroll
        for (int ni = 0; ni < 4; ++ni) {
          float v = acc[mi][ni][reg];
          ss += v * v;
        }
        ss += __shfl_xor(ss, 1); ss += __shfl_xor(ss, 2);
        ss += __shfl_xor(ss, 4); ss += __shfl_xor(ss, 8);
        const float inv = 1.f / fmaxf(sqrtf(ss), 1e-12f);
        const int mrow = row0 + (w << 5) + (mi << 4) + (quad << 2) + reg;
        const int n = mrow & 1023, b = mrow >> 10;
#pragma unroll
        for (int ni = 0; ni < 4; ++ni) {
          int d = (ni << 4) + m;
          float vn = acc[mi][ni][reg] * inv * scale[h6 + d];
          float other = __shfl_xor(vn, 1);
          float rot = (d & 1) ? other : -other;
          float f = freqs[(n << 6) + d];
          float o = (vn * __cosf(f) + rot * __sinf(f)) * mulf;
          if (sector == 0)
            qb[((size_t)mrow << 10) + h6 + d] = to_bf(o);
          else
            kall[(size_t)(b * 1056 + 16 + n) * 1024 + h6 + d] = to_bf(o);
        }
      }
  } else {
#pragma unroll
    for (int mi = 0; mi < 2; ++mi)
#pragma unroll
      for (int ni = 0; ni < 4; ++ni)
#pragma unroll
        for (int reg = 0; reg < 4; ++reg) {
          int mrow = row0 + (w << 5) + (mi << 4) + (quad << 2) + reg;
          int nl = (col0 & 1023) + (ni << 4) + m;
          float v = acc[mi][ni][reg];
          if (sector == 2) {
            int bb = mrow >> 10, nn = mrow & 1023;
            vallT[((size_t)((bb << 10) + nl)) * 1056 + 16 + nn] = to_bf(v);
          } else {
            float s = v + b_vg[nl];
            vgbuf[((size_t)mrow << 10) + nl] = 1.f / (1.f + __expf(-s));
          }
        }
  }
}

// ---- fused head-gate projection: hg = sigmoid(x @ W_hg + b_hg) -------------
__global__ __launch_bounds__(256)
void hgate_proj(const float* __restrict__ x, const float* __restrict__ W,
                const float* __restrict__ bias, float* __restrict__ hg)
{
  int G = blockIdx.x * 256 + threadIdx.x;
  int row = G >> 4, h = G & 15;
  const float4* x4 = (const float4*)(x + ((size_t)row << 10));
  float acc = 0.f;
#pragma unroll 4
  for (int k4 = 0; k4 < 256; ++k4) {
    float4 xv = x4[k4];
    int kb = k4 << 2;
    acc += xv.x * W[(kb + 0) * 16 + h] + xv.y * W[(kb + 1) * 16 + h]
         + xv.z * W[(kb + 2) * 16 + h] + xv.w * W[(kb + 3) * 16 + h];
  }
  float v = acc + bias[h];
  hg[(row << 4) + h] = 1.f / (1.f + __expf(-v));
}

// ------ memory slots into kall rows 0..15 and vallT cols 0..15 --------------
__global__ __launch_bounds__(256)
void mem_build(const float* __restrict__ mem_k, const float* __restrict__ mem_v,
               const float* __restrict__ k_scale,
               unsigned short* __restrict__ kall, unsigned short* __restrict__ vallT)
{
  int gid = blockIdx.x * 256 + threadIdx.x;   // 16384 = H*M*64
  int d = gid & 63;
  int row = gid >> 6;            // h*M + mm
  int h = row >> 4, mm = row & 15;
  float v = mem_k[gid];
  float ss = v * v;
#pragma unroll
  for (int off = 32; off; off >>= 1) ss += __shfl_xor(ss, off);
  unsigned short kb = to_bf(v / fmaxf(sqrtf(ss), 1e-12f) * k_scale[(h << 6) + d]);
  unsigned short vb = to_bf(mem_v[gid]);
#pragma unroll
  for (int b = 0; b < 4; ++b) {
    kall[(size_t)(b * 1056 + mm) * 1024 + (h << 6) + d] = kb;
    vallT[(size_t)((b << 10) + (h << 6) + d) * 1056 + mm] = vb;
  }
}

// ================= two-pass MFMA attention, flat-balanced ===================
// R18: XCD-aware block swizzle. FETCH 150MB == 2176 units x 64KB K/V tiles ->
// K/V reads are HBM misses (~900cyc each, ~8 serialized pairs/unit = the 70%
// stall). Cause: round-robin block->XCD dispatch mixes ~3 batches per XCD L2
// (13MB >> 4MB). Remap blk=(raw&7)*96+raw/8 (bijective, 768=8x96): each XCD
// owns a contiguous range = half of ONE batch -> working set kall(b)+vallT(b)
// = 4.4MB ~ L2. Attention math untouched (R7-hardened).

// ---- pass 1: denominators L[b][i][g] via atomicAdd -------------------------
__global__ __launch_bounds__(256)
void attn_lsum(const unsigned short* __restrict__ qb, const unsigned short* __restrict__ kall,
               const float* __restrict__ W_pre, float* __restrict__ Lbuf)
{
  __shared__ float sS[16 * 16 * 32];            // [h][i][j 0..31], swizzled cols
  __shared__ f32x4 sWpre4[64];

  const int t = threadIdx.x, lane = t & 63, w = t >> 6;
  const int m = lane & 15, quad = lane >> 4;
  if (t < 64) {
    int h = t >> 2, p4 = t & 3;
    sWpre4[t] = (f32x4){W_pre[(4 * p4 + 0) * 16 + h], W_pre[(4 * p4 + 1) * 16 + h],
                        W_pre[(4 * p4 + 2) * 16 + h], W_pre[(4 * p4 + 3) * 16 + h]};
  }

  const int raw = blockIdx.x;                   // grid 768 = 8 XCD x 96
  const int blk = (raw & 7) * 96 + (raw >> 3);  // XCD-grouped contiguous ranges
  const int u0 = (4352 * blk) / 768, u1 = (4352 * (blk + 1)) / 768;
  if (u0 == u1) return;

  int accu = 0, bi = 0;
  while (true) {
    int un = (((bi & 63) + 1) >> 1) + 1;
    if (accu + un > u0) break;
    accu += un; ++bi;
  }
  int b = bi >> 6, it = bi & 63, uoff = u0 - accu;

  short8 afr[4][2];
  float partL[16];
  bool fresh = true;

  for (int u = u0; u < u1; ++u) {
    const int i0 = it << 4;
    if (fresh) {
#pragma unroll
      for (int hh = 0; hh < 4; ++hh)
#pragma unroll
        for (int kk = 0; kk < 2; ++kk)
          afr[hh][kk] = *(const short8*)(qb + (((size_t)(b << 10) + i0 + m) << 10)
                                         + ((w << 2) + hh) * 64 + kk * 32 + quad * 8);
#pragma unroll
      for (int g = 0; g < 16; ++g) partL[g] = 0.f;
      fresh = false;
    }
    const int j0 = uoff << 5;
    // ---- QK: both 16-j subtiles -> sS ----
#pragma unroll
    for (int sub = 0; sub < 2; ++sub) {
      const int js = j0 + (sub << 4);
#pragma unroll
      for (int hh = 0; hh < 4; ++hh) {
        f32x4 s = (f32x4){0.f, 0.f, 0.f, 0.f};
#pragma unroll
        for (int kk = 0; kk < 2; ++kk) {
          short8 bfr = *(const short8*)(kall + ((size_t)(b * 1056 + js + m) << 10)
                                        + ((w << 2) + hh) * 64 + kk * 32 + quad * 8);
          s = __builtin_amdgcn_mfma_f32_16x16x32_bf16(afr[hh][kk], bfr, s, 0, 0, 0);
        }
#pragma unroll
        for (int reg = 0; reg < 4; ++reg) {
          int irow = (quad << 2) + reg;
          sS[(((w << 2) + hh) * 16 + irow) * 32 + (((sub << 4) + m) ^ SWZS(irow))] = s[reg];
        }
      }
    }
    __syncthreads();
    // ---- packed premix + exp; 2 columns per thread ----
    {
      const int i_l = t >> 4, j_l = t & 15;
      const int ig = i0 + i_l;
      const int vs = SWZS(i_l);
      const int sc0 = j_l ^ vs, sc1 = (16 + j_l) ^ vs;
      float ch0[16], ch1[16];
#pragma unroll
      for (int h = 0; h < 16; ++h) {
        ch0[h] = sS[(h * 16 + i_l) * 32 + sc0];
        ch1[h] = sS[(h * 16 + i_l) * 32 + sc1];
      }
      f32x4 a0[4], a1[4];
#pragma unroll
      for (int p = 0; p < 4; ++p) { a0[p] = (f32x4){0.f,0.f,0.f,0.f}; a1[p] = a0[p]; }
#pragma unroll
      for (int h = 0; h < 16; ++h) {
        float c0 = ch0[h], c1 = ch1[h];
#pragma unroll
        for (int p = 0; p < 4; ++p) {
          f32x4 wv = sWpre4[(h << 2) + p];
          a0[p] += wv * c0;
          a1[p] += wv * c1;
        }
      }
      const bool ok0 = (j0 + j_l) <= ig + 16;
      const bool ok1 = (j0 + 16 + j_l) <= ig + 16;
#pragma unroll
      for (int p = 0; p < 4; ++p)
#pragma unroll
        for (int e = 0; e < 4; ++e) {
          float v0 = ok0 ? __expf(a0[p][e] - 20.f) : 0.f;
          float v1 = ok1 ? __expf(a1[p][e] - 20.f) : 0.f;
          partL[(p << 2) + e] += v0 + v1;
        }
    }
    __syncthreads();
    ++uoff;
    if (uoff == ((it + 1) >> 1) + 1) {
#pragma unroll
      for (int g = 0; g < 16; ++g) {
        float v = partL[g];
        v += __shfl_xor(v, 1); v += __shfl_xor(v, 2);
        v += __shfl_xor(v, 4); v += __shfl_xor(v, 8);
        if (m == 0)
          atomicAdd(&Lbuf[(((size_t)(b << 10) + i0 + (w << 2) + quad) << 4) + g], v);
      }
      ++bi; b = bi >> 6; it = bi & 63; uoff = 0; fresh = true;
    }
  }
  if (!fresh) {
    const int i0 = it << 4;
#pragma unroll
    for (int g = 0; g < 16; ++g) {
      float v = partL[g];
      v += __shfl_xor(v, 1); v += __shfl_xor(v, 2);
      v += __shfl_xor(v, 4); v += __shfl_xor(v, 8);
      if (m == 0)
        atomicAdd(&Lbuf[(((size_t)(b << 10) + i0 + (w << 2) + quad) << 4) + g], v);
    }
  }
}

// ---- pass 2: recompute, normalize, W_post per column, PV with v[g2] --------
__global__ __launch_bounds__(256)
void attn_pv2(const unsigned short* __restrict__ qb, const unsigned short* __restrict__ kall,
              const unsigned short* __restrict__ vallT, const float* __restrict__ W_pre,
              const float* __restrict__ W_post, const float* __restrict__ Lbuf,
              float* __restrict__ Obuf)
{
  __shared__ float sS[16 * 16 * 32];            // [h][i][j 0..31], swizzled cols
  __shared__ __align__(16) unsigned short sE[16 * 16 * 32]; // bf16 p2, granule-swizzled
  __shared__ f32x4 sWpre4[64], sWpost4[64];
  __shared__ float sIL[256];

  const int t = threadIdx.x, lane = t & 63, w = t >> 6;
  const int m = lane & 15, quad = lane >> 4;
  if (t < 64) {
    int h = t >> 2, p4 = t & 3;
    sWpre4[t]  = (f32x4){W_pre[(4 * p4 + 0) * 16 + h],  W_pre[(4 * p4 + 1) * 16 + h],
                         W_pre[(4 * p4 + 2) * 16 + h],  W_pre[(4 * p4 + 3) * 16 + h]};
    sWpost4[t] = (f32x4){W_post[(4 * p4 + 0) * 16 + h], W_post[(4 * p4 + 1) * 16 + h],
                         W_post[(4 * p4 + 2) * 16 + h], W_post[(4 * p4 + 3) * 16 + h]};
  }

  const int raw = blockIdx.x;                   // grid 768 = 8 XCD x 96
  const int blk = (raw & 7) * 96 + (raw >> 3);  // XCD-grouped contiguous ranges
  const int u0 = (4352 * blk) / 768, u1 = (4352 * (blk + 1)) / 768;
  if (u0 == u1) return;

  int accu = 0, bi = 0;
  while (true) {
    int un = (((bi & 63) + 1) >> 1) + 1;
    if (accu + un > u0) break;
    accu += un; ++bi;
  }
  int b = bi >> 6, it = bi & 63, uoff = u0 - accu;

  short8 afr[4][2];
  f32x4 oacc[4][4];
  bool fresh = true;

  for (int u = u0; u < u1; ++u) {
    const int i0 = it << 4;
    if (fresh) {
#pragma unroll
      for (int hh = 0; hh < 4; ++hh)
#pragma unroll
        for (int kk = 0; kk < 2; ++kk)
          afr[hh][kk] = *(const short8*)(qb + (((size_t)(b << 10) + i0 + m) << 10)
                                         + ((w << 2) + hh) * 64 + kk * 32 + quad * 8);
#pragma unroll
      for (int a = 0; a < 4; ++a)
#pragma unroll
        for (int dt = 0; dt < 4; ++dt) oacc[a][dt] = (f32x4){0.f, 0.f, 0.f, 0.f};
      sIL[t] = 1.f / Lbuf[(((size_t)(b << 10) + i0 + (t >> 4)) << 4) + (t & 15)];
      fresh = false;
    }
    const int j0 = uoff << 5;
    // ---- QK: both 16-j subtiles -> sS ----
#pragma unroll
    for (int sub = 0; sub < 2; ++sub) {
      const int js = j0 + (sub << 4);
#pragma unroll
      for (int hh = 0; hh < 4; ++hh) {
        f32x4 s = (f32x4){0.f, 0.f, 0.f, 0.f};
#pragma unroll
        for (int kk = 0; kk < 2; ++kk) {
          short8 bfr = *(const short8*)(kall + ((size_t)(b * 1056 + js + m) << 10)
                                        + ((w << 2) + hh) * 64 + kk * 32 + quad * 8);
          s = __builtin_amdgcn_mfma_f32_16x16x32_bf16(afr[hh][kk], bfr, s, 0, 0, 0);
        }
#pragma unroll
        for (int reg = 0; reg < 4; ++reg) {
          int irow = (quad << 2) + reg;
          sS[(((w << 2) + hh) * 16 + irow) * 32 + (((sub << 4) + m) ^ SWZS(irow))] = s[reg];
        }
      }
    }
    __syncthreads();   // also covers sIL write at fresh
    // ---- packed premix + exp + normalize + packed W_post -> p2 bf16 ----
    {
      const int i_l = t >> 4, j_l = t & 15;
      const int ig = i0 + i_l;
      const int vs = SWZS(i_l);
      const int sc0 = j_l ^ vs, sc1 = (16 + j_l) ^ vs;
      const int r3s = i_l & 3;
      const int eo0 = ((((j_l >> 3) ^ r3s) << 3) | (j_l & 7));
      const int eo1 = ((((2 + (j_l >> 3)) ^ r3s) << 3) | (j_l & 7));
      float ch0[16], ch1[16];
#pragma unroll
      for (int h = 0; h < 16; ++h) {
        ch0[h] = sS[(h * 16 + i_l) * 32 + sc0];
        ch1[h] = sS[(h * 16 + i_l) * 32 + sc1];
      }
      f32x4 a0[4], a1[4];
#pragma unroll
      for (int p = 0; p < 4; ++p) { a0[p] = (f32x4){0.f,0.f,0.f,0.f}; a1[p] = a0[p]; }
#pragma unroll
      for (int h = 0; h < 16; ++h) {
        float c0 = ch0[h], c1 = ch1[h];
#pragma unroll
        for (int p = 0; p < 4; ++p) {
          f32x4 wv = sWpre4[(h << 2) + p];
          a0[p] += wv * c0;
          a1[p] += wv * c1;
        }
      }
      const bool ok0 = (j0 + j_l) <= ig + 16;
      const bool ok1 = (j0 + 16 + j_l) <= ig + 16;
      float e0[16], e1[16];
#pragma unroll
      for (int p = 0; p < 4; ++p)
#pragma unroll
        for (int e = 0; e < 4; ++e) {
          int g = (p << 2) + e;
          float il = sIL[(i_l << 4) + g];
          e0[g] = ok0 ? __expf(a0[p][e] - 20.f) * il : 0.f;
          e1[g] = ok1 ? __expf(a1[p][e] - 20.f) * il : 0.f;
        }
      f32x4 b0[4], b1[4];
#pragma unroll
      for (int p = 0; p < 4; ++p) { b0[p] = (f32x4){0.f,0.f,0.f,0.f}; b1[p] = b0[p]; }
#pragma unroll
      for (int g = 0; g < 16; ++g) {
        float c0 = e0[g], c1 = e1[g];
#pragma unroll
        for (int p = 0; p < 4; ++p) {
          f32x4 wv = sWpost4[(g << 2) + p];
          b0[p] += wv * c0;
          b1[p] += wv * c1;
        }
      }
#pragma unroll
      for (int p = 0; p < 4; ++p)
#pragma unroll
        for (int e = 0; e < 4; ++e) {
          int g2 = (p << 2) + e;
          sE[(g2 * 16 + i_l) * 32 + eo0] = to_bf(b0[p][e]);
          sE[(g2 * 16 + i_l) * 32 + eo1] = to_bf(b1[p][e]);
        }
    }
    __syncthreads();
    // ---- PV: wave w owns g2 = 4w..4w+3; V indexed by g2 (output head) ----
#pragma unroll
    for (int gl = 0; gl < 4; ++gl) {
      const int g2 = (w << 2) + gl;
      short8 a = *(const short8*)(sE + (g2 * 16 + m) * 32 + ((quad ^ (m & 3)) << 3));
#pragma unroll
      for (int dt = 0; dt < 4; ++dt) {
        short8 bv = *(const short8*)(vallT + ((size_t)((b << 10) + g2 * 64 + dt * 16 + m)) * 1056
                                     + j0 + quad * 8);
        oacc[gl][dt] = __builtin_amdgcn_mfma_f32_16x16x32_bf16(a, bv, oacc[gl][dt], 0, 0, 0);
      }
    }
    ++uoff;
    if (uoff == ((it + 1) >> 1) + 1) {
#pragma unroll
      for (int gl = 0; gl < 4; ++gl) {
        int g2 = (w << 2) + gl;
#pragma unroll
        for (int dt = 0; dt < 4; ++dt)
#pragma unroll
          for (int reg = 0; reg < 4; ++reg)
            atomicAdd(&Obuf[(((size_t)(b << 10) + i0 + (quad << 2) + reg) << 10)
                            + g2 * 64 + dt * 16 + m], oacc[gl][dt][reg]);
      }
      ++bi; b = bi >> 6; it = bi & 63; uoff = 0; fresh = true;
    }
  }
  if (!fresh) {
    const int i0 = it << 4;
#pragma unroll
    for (int gl = 0; gl < 4; ++gl) {
      int g2 = (w << 2) + gl;
#pragma unroll
      for (int dt = 0; dt < 4; ++dt)
#pragma unroll
        for (int reg = 0; reg < 4; ++reg)
          atomicAdd(&Obuf[(((size_t)(b << 10) + i0 + (quad << 2) + reg) << 10)
                          + g2 * 64 + dt * 16 + m], oacc[gl][dt][reg]);
    }
  }
}

// ---- epilogue: aob = Obuf * hgate * vgate (bf16) ---------------------------
__global__ __launch_bounds__(256)
void gate_out(const float* __restrict__ Obuf, const float* __restrict__ hgate,
              const float* __restrict__ vgate, unsigned short* __restrict__ aob)
{
  int i4 = blockIdx.x * 256 + threadIdx.x;   // 1048576 float4 groups
  float4 o = ((const float4*)Obuf)[i4];
  int base = i4 << 2;
  int row = base >> 10, hd = base & 1023, h = hd >> 6;
  float hg = hgate[(row << 4) + h];
  float4 vg = ((const float4*)vgate)[i4];
  ushort4 r;
  r.x = to_bf(o.x * hg * vg.x);
  r.y = to_bf(o.y * hg * vg.y);
  r.z = to_bf(o.z * hg * vg.z);
  r.w = to_bf(o.w * hg * vg.w);
  ((ushort4*)aob)[i4] = r;
}

extern "C" void kernel_launch(void* const* d_in, const int* in_sizes, int n_in,
                              void* d_out, int out_size, void* d_ws, size_t ws_size,
                              hipStream_t stream)
{
  const float* x       = (const float*)d_in[0];
  const float* freqs   = (const float*)d_in[1];
  const float* Wq      = (const float*)d_in[2];
  const float* Wk      = (const float*)d_in[3];
  const float* Wv      = (const float*)d_in[4];
  const float* q_scale = (const float*)d_in[5];
  const float* k_scale = (const float*)d_in[6];
  const float* mem_k   = (const float*)d_in[7];
  const float* mem_v   = (const float*)d_in[8];
  const float* W_pre   = (const float*)d_in[9];
  const float* W_post  = (const float*)d_in[10];
  const float* W_hg    = (const float*)d_in[11];
  const float* b_hg    = (const float*)d_in[12];
  const float* W_vg    = (const float*)d_in[13];
  const float* b_vg    = (const float*)d_in[14];
  const float* Wo      = (const float*)d_in[15];
  float* out = (float*)d_out;
  float* ws  = (float*)d_ws;

  // workspace (float offsets), total 19,660,800 f = 78.6 MiB -- R17 map:
  unsigned short* wb4  = (unsigned short*)ws;
  unsigned short* qb   = (unsigned short*)(ws + 2097152);
  float* Obuf  = ws + 4194304;
  float* vgbuf = ws + 8388608;
  float* hgbuf = ws + 12582912;
  float* Lbuf  = ws + 12648448;
  unsigned short* xb    = (unsigned short*)(ws + 12713984);
  unsigned short* kall  = (unsigned short*)(ws + 14811136);
  unsigned short* vallT = (unsigned short*)(ws + 16973824);
  unsigned short* wbo   = (unsigned short*)(ws + 19136512);
  unsigned short* aob   = (unsigned short*)ws;

  dim3 blk(256);
  cvt_bf16x4<<<4096, blk, 0, stream>>>(x, xb, 1048576);
  // fused head-gate projection (fp32, reads original x)
  hgate_proj<<<256, blk, 0, stream>>>(x, W_hg, b_hg, hgbuf);
  // fused QKVG projection + q/k postprocess: one transpose batch + one GEMM
  transpose4_to_bf<<<dim3(16, 16, 4), blk, 0, stream>>>(Wq, Wk, Wv, W_vg, wb4);
  gemm_qkvg<<<dim3(64, 32), blk, 0, stream>>>(xb, wb4, q_scale, k_scale, freqs,
                                              qb, kall, vallT, vgbuf, b_vg);
  // memory slots (disjoint rows/cols of kall/vallT)
  mem_build<<<64, blk, 0, stream>>>(mem_k, mem_v, k_scale, kall, vallT);
  // zero Lbuf and Obuf
  hipMemsetAsync(Lbuf, 0, 65536 * sizeof(float), stream);
  hipMemsetAsync(Obuf, 0, 4194304 * sizeof(float), stream);
  // two-pass attention + gate epilogue
  attn_lsum<<<768, blk, 0, stream>>>(qb, kall, W_pre, Lbuf);
  attn_pv2<<<768, blk, 0, stream>>>(qb, kall, vallT, W_pre, W_post, Lbuf, Obuf);
  gate_out<<<4096, blk, 0, stream>>>(Obuf, hgbuf, vgbuf, aob);
  // output projection
  transpose_to_bf<<<dim3(16, 16), blk, 0, stream>>>(Wo, wbo);
  gemm_bf128<<<dim3(16, 32), blk, 0, stream>>>(aob, wbo, out);
}